// Round 3
// baseline (371.905 us; speedup 1.0000x reference)
//
#include <hip/hip_runtime.h>

// MultiHead attention, B=4 L=2048 D=1024 H=16 HD=64.
// R11: attn4 issue-diet on top of R10's swizzle (conflicts measured 0).
// (1) lsum via ones-A MFMA on the packed P B-frag (col=lane&15=r16 = this
//     lane's q, same mapping the PV path already validates); kills 1024 fp32
//     adds/wave + the epilogue shfl pair. pk2p (round-half-up, proven) kept
//     for ALL bf16 packing — R9 showed v_cvt_pk_bf16_f32 is RTZ-class.
// (2) LDS double-buffered [2][64][64] (32KB), ONE barrier per k-tile:
//     iter t: issue loads t+1 -> compute buf[t&1] -> write buf[t&1^1] -> bar.
//     Reads of buf X in iter t are fenced from the overwrite in iter t+1 by
//     the end-of-t barrier. Removes the serial sync->ds_write->sync phase.
// (3) s_setprio(1) around QK and PV MFMA clusters (T5, m191 attn +4-7%).

#define Bsz 4
#define Lq 2048
#define Dm 1024
#define NH 16
#define HD 64
// 0.125 * log2(e): folded into Wq/bq so attention uses exp2 directly
#define QSCALE 0.18033688011112042f

typedef unsigned short u16;
typedef __attribute__((ext_vector_type(4))) short bf16x4;
typedef __attribute__((ext_vector_type(8))) short short8;
typedef __attribute__((ext_vector_type(4))) float f32x4;

#define MFMA32(a, b, c) __builtin_amdgcn_mfma_f32_16x16x32_bf16(a, b, c, 0, 0, 0)

typedef __attribute__((address_space(3))) unsigned su32;
typedef __attribute__((address_space(1))) unsigned gu32;
__device__ __forceinline__ void gl_lds16(const u16* g, u16* l) {
  __builtin_amdgcn_global_load_lds((gu32*)(g), (su32*)(l), 16, 0, 0);
}

__device__ __forceinline__ u16 f2b(float x) {
  unsigned u = __builtin_bit_cast(unsigned, x);
  return (u16)((u + 0x7fffu + ((u >> 16) & 1u)) >> 16);  // RNE
}
__device__ __forceinline__ unsigned pk2(float a, float b) {
  return (unsigned)f2b(a) | ((unsigned)f2b(b) << 16);
}
// round-half-up bf16 pair pack via v_perm: lo=bf16(a), hi=bf16(b)
__device__ __forceinline__ unsigned pk2p(float a, float b) {
  return __builtin_amdgcn_perm(__builtin_bit_cast(unsigned, b) + 0x8000u,
                               __builtin_bit_cast(unsigned, a) + 0x8000u, 0x07060302u);
}
__device__ __forceinline__ float fexp2(float x) {
#if __has_builtin(__builtin_amdgcn_exp2f)
  return __builtin_amdgcn_exp2f(x);
#else
  return exp2f(x);
#endif
}

// ---------------- fused triple activation cast fp32 -> bf16 ----------------
__global__ void castk3(const float* __restrict__ q, const float* __restrict__ k,
                       const float* __restrict__ v, u16* __restrict__ dst) {
  const float* s = blockIdx.y == 0 ? q : (blockIdx.y == 1 ? k : v);
  u16* d = dst + (size_t)blockIdx.y * (Bsz * Lq * Dm);
  int i = (blockIdx.x * 256 + threadIdx.x) * 8;
  float4 a = *(const float4*)(s + i);
  float4 b = *(const float4*)(s + i + 4);
  short8 o;
  o[0] = (short)f2b(a.x); o[1] = (short)f2b(a.y);
  o[2] = (short)f2b(a.z); o[3] = (short)f2b(a.w);
  o[4] = (short)f2b(b.x); o[5] = (short)f2b(b.y);
  o[6] = (short)f2b(b.z); o[7] = (short)f2b(b.w);
  *(short8*)(d + i) = o;
}

// fused 4-weight cast, blockIdx.y selects matrix
__global__ void castw(const float* __restrict__ s0, const float* __restrict__ s1,
                      const float* __restrict__ s2, const float* __restrict__ s3,
                      u16* __restrict__ d0, u16* __restrict__ d1,
                      u16* __restrict__ d2, u16* __restrict__ d3) {
  const float* s; u16* d; float sc = 1.0f;
  switch (blockIdx.y) {
    case 0: s = s0; d = d0; sc = QSCALE; break;
    case 1: s = s1; d = d1; break;
    case 2: s = s2; d = d2; break;
    default: s = s3; d = d3; break;
  }
  int i = (blockIdx.x * 256 + threadIdx.x) * 8;
  float4 a = *(const float4*)(s + i);
  float4 b = *(const float4*)(s + i + 4);
  short8 o;
  o[0] = (short)f2b(a.x * sc); o[1] = (short)f2b(a.y * sc);
  o[2] = (short)f2b(a.z * sc); o[3] = (short)f2b(a.w * sc);
  o[4] = (short)f2b(b.x * sc); o[5] = (short)f2b(b.y * sc);
  o[6] = (short)f2b(b.z * sc); o[7] = (short)f2b(b.w * sc);
  *(short8*)(d + i) = o;
}

// ---------------- fused QKV projection GEMM ----------------
// grid (8, 64, 3). z: {q->Qh (scaled), k->Kh, v->Vtg (transposed+permuted)}.
__global__ __launch_bounds__(256) void qkv_gemm(
    const u16* __restrict__ Ab,
    const u16* __restrict__ Wqb, const u16* __restrict__ Wkb, const u16* __restrict__ Wvb,
    const float* __restrict__ bq, const float* __restrict__ bk, const float* __restrict__ bv,
    u16* __restrict__ Qh, u16* __restrict__ Kh, u16* __restrict__ Vtg)
{
  __shared__ __align__(16) u16 As[128 * 32];
  __shared__ __align__(16) u16 Bs[128 * 32];
  const int z = blockIdx.z;
  const u16* A  = Ab + (size_t)z * (Bsz * Lq * Dm);
  const u16* Bt = z == 0 ? Wqb : (z == 1 ? Wkb : Wvb);
  const float* bias = z == 0 ? bq : (z == 1 ? bk : bv);
  const float bscale = z == 0 ? QSCALE : 1.0f;

  const int tid  = threadIdx.x;
  const int lane = tid & 63;
  const int wave = tid >> 6;
  const int quad = lane >> 4;
  const int r16  = lane & 15;
  const int wm   = (wave >> 1) * 64;
  const int wn   = (wave & 1) * 64;
  const int m0   = blockIdx.y * 128;
  const int n0   = blockIdx.x * 128;

  const u16* ga = A  + (size_t)(m0 + wave * 32 + (lane >> 2)) * Dm + (lane & 3) * 8;
  const u16* gb = Bt + (size_t)(n0 + wave * 32 + (lane >> 2)) * Dm + (lane & 3) * 8;
  u16* la = As + wave * 1024;
  u16* lb = Bs + wave * 1024;

  f32x4 acc[4][4] = {};

  for (int k0 = 0; k0 < Dm; k0 += 32) {
    gl_lds16(ga + k0, la);
    gl_lds16(ga + k0 + 16 * Dm, la + 512);
    gl_lds16(gb + k0, lb);
    gl_lds16(gb + k0 + 16 * Dm, lb + 512);
    __syncthreads();

    short8 af[4], bfr[4];
#pragma unroll
    for (int mt = 0; mt < 4; ++mt) af[mt]  = *(const short8*)&As[(wm + mt * 16 + r16) * 32 + quad * 8];
#pragma unroll
    for (int nt = 0; nt < 4; ++nt) bfr[nt] = *(const short8*)&Bs[(wn + nt * 16 + r16) * 32 + quad * 8];
#pragma unroll
    for (int mt = 0; mt < 4; ++mt)
#pragma unroll
      for (int nt = 0; nt < 4; ++nt)
        acc[mt][nt] = MFMA32(af[mt], bfr[nt], acc[mt][nt]);
    __syncthreads();
  }

#pragma unroll
  for (int mt = 0; mt < 4; ++mt) {
#pragma unroll
    for (int nt = 0; nt < 4; ++nt) {
      int n = n0 + wn + nt * 16 + r16;
      float bv_ = bias[n] * bscale;
      if (z == 2) {
        // V: transposed head-split Vtg[bh][d][l'], column-permuted within each
        // 32-block: l' = (l&~31) | q<<3 | w<<2 | j  (q=(l>>2)&3, w=(l>>4)&1)
        // so attention's b128 A-frag slot (quad,i=4w+j) carries the kpos that
        // the P B-frag holds in the same slot.
        int m_base = m0 + wm + mt * 16 + quad * 4;
        int b = m_base >> 11, l0 = m_base & 2047;
        int lp = (l0 & ~31) | (((l0 >> 2) & 3) << 3) | (((l0 >> 4) & 1) << 2);
        int h = n >> 6, d = n & 63;
        u16* dst = Vtg + (((size_t)(b * NH + h)) * HD + d) * Lq + lp;
        uint2 pkd;
        pkd.x = pk2(acc[mt][nt][0] + bv_, acc[mt][nt][1] + bv_);
        pkd.y = pk2(acc[mt][nt][2] + bv_, acc[mt][nt][3] + bv_);
        *(uint2*)dst = pkd;
      } else {
        u16* dst = z == 0 ? Qh : Kh;
#pragma unroll
        for (int j = 0; j < 4; ++j) {
          int m = m0 + wm + mt * 16 + quad * 4 + j;
          int b = m >> 11, l = m & 2047;
          int h = n >> 6,  d = n & 63;
          dst[(((size_t)(b * NH + h)) * Lq + l) * HD + d] = f2b(acc[mt][nt][j] + bv_);
        }
      }
    }
  }
}

// ---------------- Wo GEMM: 128x64 tile, fp32 out ----------------
__global__ __launch_bounds__(256) void gemm_wo(
    const u16* __restrict__ A, const u16* __restrict__ Bt,
    const float* __restrict__ bias, float* __restrict__ C)
{
  __shared__ __align__(16) u16 As[128 * 32];
  __shared__ __align__(16) u16 Bs[64 * 32];
  const int tid  = threadIdx.x;
  const int lane = tid & 63;
  const int wave = tid >> 6;
  const int quad = lane >> 4;
  const int r16  = lane & 15;
  const int wm   = wave * 32;
  const int m0   = blockIdx.y * 128;
  const int n0   = blockIdx.x * 64;

  const u16* ga = A  + (size_t)(m0 + wave * 32 + (lane >> 2)) * Dm + (lane & 3) * 8;
  const u16* gb = Bt + (size_t)(n0 + wave * 16 + (lane >> 2)) * Dm + (lane & 3) * 8;
  u16* la = As + wave * 1024;
  u16* lb = Bs + wave * 512;

  f32x4 acc[2][4] = {};

  for (int k0 = 0; k0 < Dm; k0 += 32) {
    gl_lds16(ga + k0, la);
    gl_lds16(ga + k0 + 16 * Dm, la + 512);
    gl_lds16(gb + k0, lb);
    __syncthreads();

    short8 af[2], bfr[4];
#pragma unroll
    for (int mt = 0; mt < 2; ++mt) af[mt]  = *(const short8*)&As[(wm + mt * 16 + r16) * 32 + quad * 8];
#pragma unroll
    for (int nt = 0; nt < 4; ++nt) bfr[nt] = *(const short8*)&Bs[(nt * 16 + r16) * 32 + quad * 8];
#pragma unroll
    for (int mt = 0; mt < 2; ++mt)
#pragma unroll
      for (int nt = 0; nt < 4; ++nt)
        acc[mt][nt] = MFMA32(af[mt], bfr[nt], acc[mt][nt]);
    __syncthreads();
  }

#pragma unroll
  for (int mt = 0; mt < 2; ++mt) {
#pragma unroll
    for (int nt = 0; nt < 4; ++nt) {
      int n = n0 + nt * 16 + r16;
      float bv = bias[n];
#pragma unroll
      for (int j = 0; j < 4; ++j) {
        int m = m0 + wm + mt * 16 + quad * 4 + j;
        C[(size_t)m * Dm + n] = acc[mt][nt][j] + bv;
      }
    }
  }
}

// ---------------- fused flash attention (S^T form, K=32 PV) ----------------
// Qh (pre-scaled), Kh: [bh][L][HD] bf16. Vtg: [bh][HD][L] bf16, col-permuted.
// Oa: [B*L][D] bf16 row-major. Block: 4 waves x 32 q = 128 q; k-tiles of 64.
// LDS double-buffered + XOR-swizzled (16B chunk c of row r at chunk c^(r&7)).
__global__ __launch_bounds__(256) void attn4(
    const u16* __restrict__ Qh, const u16* __restrict__ Kh,
    const u16* __restrict__ Vtg, u16* __restrict__ Oa)
{
  const int bh = blockIdx.y;   // 0..63
  const int qt = blockIdx.x;   // 0..15
  const int tid = threadIdx.x, lane = tid & 63, wave = tid >> 6;
  const int quad = lane >> 4, r16 = lane & 15;

  __shared__ __align__(16) u16 Ks[2][64][64];   // [buf][kpos][d], chunk-swizzled
  __shared__ __align__(16) u16 Vt[2][64][64];   // [buf][d][kpos'] (permuted), chunk-swizzled

  const int qbase = qt * 128 + wave * 32;
  short8 aq[2][2];
#pragma unroll
  for (int qf = 0; qf < 2; ++qf) {
    const size_t qrow = ((size_t)bh * Lq + qbase + qf * 16 + r16) * HD;
    aq[qf][0] = *(const short8*)(Qh + qrow + quad * 8);
    aq[qf][1] = *(const short8*)(Qh + qrow + 32 + quad * 8);
  }

  const short8 ones8 = {0x3F80, 0x3F80, 0x3F80, 0x3F80, 0x3F80, 0x3F80, 0x3F80, 0x3F80};

  f32x4 oacc[2][4] = {};
  f32x4 lacc[2] = {};   // ones*P: every row = column sum of P; col = r16 = own q

  const int srow = tid >> 2;        // 0..63
  const int sc0  = (tid & 3) * 2;   // even chunk index (16B chunks, 8 per row)
  const int ssw  = srow & 7;
  const int wr0  = srow * 64 + ((sc0    ) ^ ssw) * 8;  // element offset in one buffer
  const int wr1  = srow * 64 + ((sc0 + 1) ^ ssw) * 8;
  u16* ksb = &Ks[0][0][0];
  u16* vtb = &Vt[0][0][0];

  const u16* kg = Kh  + ((size_t)bh * Lq + srow) * HD + (tid & 3) * 16;
  const u16* vg = Vtg + ((size_t)bh * HD + srow) * Lq + (tid & 3) * 16;

  short8 pk0 = *(const short8*)(kg);
  short8 pk1 = *(const short8*)(kg + 8);
  short8 pv0 = *(const short8*)(vg);
  short8 pv1 = *(const short8*)(vg + 8);

  // prologue: stage tile 0 into buffer 0
  *(short8*)(ksb + wr0) = pk0;
  *(short8*)(ksb + wr1) = pk1;
  *(short8*)(vtb + wr0) = pv0;
  *(short8*)(vtb + wr1) = pv1;
  __syncthreads();

  const int sx = r16 & 7;           // read-side swizzle key (rows are 16k+r16)

  for (int t = 0; t < 32; ++t) {
    const int cur = (t & 1) * 4096;
    const int nxt = 4096 - cur;
    if (t < 31) {
      const u16* kgn = kg + (size_t)(t + 1) * 64 * HD;
      const u16* vgn = vg + (t + 1) * 64;
      pk0 = *(const short8*)(kgn);
      pk1 = *(const short8*)(kgn + 8);
      pv0 = *(const short8*)(vgn);
      pv1 = *(const short8*)(vgn + 8);
    }

#pragma unroll
    for (int ks = 0; ks < 2; ++ks) {
      // S^T for the two 16-kpos chunks of this 32-window
      f32x4 stq[2][2];
      __builtin_amdgcn_s_setprio(1);
#pragma unroll
      for (int mtl = 0; mtl < 2; ++mtl) {
        const int mt = 2 * ks + mtl;
        short8 kf0 = *(const short8*)(ksb + cur + (mt * 16 + r16) * 64 + ((quad    ) ^ sx) * 8);
        short8 kf1 = *(const short8*)(ksb + cur + (mt * 16 + r16) * 64 + ((quad + 4) ^ sx) * 8);
#pragma unroll
        for (int qf = 0; qf < 2; ++qf) {
          f32x4 zz = {};
          zz = MFMA32(kf0, aq[qf][0], zz);
          zz = MFMA32(kf1, aq[qf][1], zz);
          stq[qf][mtl] = zz;
        }
      }
      __builtin_amdgcn_s_setprio(0);
      // V A-frags for this window (permuted layout -> direct b128)
      short8 vf[4];
#pragma unroll
      for (int nt = 0; nt < 4; ++nt)
        vf[nt] = *(const short8*)(vtb + cur + (nt * 16 + r16) * 64 + ((ks * 4 + quad) ^ sx) * 8);
      // softmax + PV at K=32; lsum rides the matrix pipe via ones-A MFMA
#pragma unroll
      for (int qf = 0; qf < 2; ++qf) {
        f32x4 sa = stq[qf][0], sb = stq[qf][1];
        float p0 = fexp2(sa[0]), p1 = fexp2(sa[1]), p2 = fexp2(sa[2]), p3 = fexp2(sa[3]);
        float p4 = fexp2(sb[0]), p5 = fexp2(sb[1]), p6 = fexp2(sb[2]), p7 = fexp2(sb[3]);
        uint4 pu;
        pu.x = pk2p(p0, p1);
        pu.y = pk2p(p2, p3);
        pu.z = pk2p(p4, p5);
        pu.w = pk2p(p6, p7);
        short8 pb = __builtin_bit_cast(short8, pu);
        __builtin_amdgcn_s_setprio(1);
        lacc[qf] = MFMA32(ones8, pb, lacc[qf]);
#pragma unroll
        for (int nt = 0; nt < 4; ++nt)
          oacc[qf][nt] = MFMA32(vf[nt], pb, oacc[qf][nt]);
        __builtin_amdgcn_s_setprio(0);
      }
    }

    if (t < 31) {
      *(short8*)(ksb + nxt + wr0) = pk0;
      *(short8*)(ksb + nxt + wr1) = pk1;
      *(short8*)(vtb + nxt + wr0) = pv0;
      *(short8*)(vtb + nxt + wr1) = pv1;
      __syncthreads();
    }
  }

  const int b = bh >> 4, h = bh & 15;
  // lacc row-sum of bf16 P (same values as the PV numerator); col=r16 matches
  // the epilogue's q = qbase + qf*16 + r16; rows identical -> take reg 0.
  float linv[2];
#pragma unroll
  for (int qf = 0; qf < 2; ++qf) linv[qf] = 1.0f / lacc[qf][0];
#pragma unroll
  for (int qf = 0; qf < 2; ++qf) {
    int q = qbase + qf * 16 + r16;
    size_t rowb = ((size_t)(b * Lq + q)) * Dm + h * HD;
#pragma unroll
    for (int nt = 0; nt < 4; ++nt) {
      f32x4 o = oacc[qf][nt];
      uint2 pkd;
      pkd.x = pk2(o[0] * linv[qf], o[1] * linv[qf]);
      pkd.y = pk2(o[2] * linv[qf], o[3] * linv[qf]);
      *(uint2*)&Oa[rowb + nt * 16 + quad * 4] = pkd;
    }
  }
}

// ---------------- launcher ----------------
extern "C" void kernel_launch(void* const* d_in, const int* in_sizes, int n_in,
                              void* d_out, int out_size, void* d_ws, size_t ws_size,
                              hipStream_t stream) {
  const float* q  = (const float*)d_in[0];
  const float* k  = (const float*)d_in[1];
  const float* v  = (const float*)d_in[2];
  const float* Wq = (const float*)d_in[3];
  const float* bq = (const float*)d_in[4];
  const float* Wk = (const float*)d_in[5];
  const float* bk = (const float*)d_in[6];
  const float* Wv = (const float*)d_in[7];
  const float* bv = (const float*)d_in[8];
  const float* Wo = (const float*)d_in[9];
  const float* bo = (const float*)d_in[10];

  const int NA = Bsz * Lq * Dm;  // 8388608
  u16* abuf = (u16*)d_ws;            // [3][M][K] activations bf16; later Oa
  u16* Qh   = abuf + (size_t)3 * NA;
  u16* Kh   = Qh   + NA;
  u16* Vtg  = Kh   + NA;
  u16* wqb  = Vtg  + NA;
  u16* wkb  = wqb  + 1048576;
  u16* wvb  = wkb  + 1048576;
  u16* wob  = wvb  + 1048576;

  castw<<<dim3(512, 4), 256, 0, stream>>>(Wq, Wk, Wv, Wo, wqb, wkb, wvb, wob);
  castk3<<<dim3(NA / 2048, 3), 256, 0, stream>>>(q, k, v, abuf);

  qkv_gemm<<<dim3(8, 64, 3), 256, 0, stream>>>(abuf, wqb, wkb, wvb, bq, bk, bv, Qh, Kh, Vtg);

  attn4<<<dim3(Lq / 128, Bsz * NH), 256, 0, stream>>>(Qh, Kh, Vtg, abuf);

  gemm_wo<<<dim3(16, 64), 256, 0, stream>>>(abuf, wob, bo, (float*)d_out);
}

// Round 4
// 364.423 us; speedup vs baseline: 1.0205x; 1.0205x over previous
//
#include <hip/hip_runtime.h>

// MultiHead attention, B=4 L=2048 D=1024 H=16 HD=64.
// R12: attn4 async staging. Single change vs R10 (362.6us, attn4 103us):
// K/V tiles staged via global_load_lds (async DMA, no VGPR round-trip, no
// ds_write phase) into a 2-deep LDS double buffer, ONE barrier per k-tile.
// XOR swizzle preserved by pre-swizzling the per-lane GLOBAL source address
// (gl_lds LDS side is linear base+lane*16): wave w, instr i, lane l writes
// row r = w*16+i*8+(l>>3), phys chunk l&7, so source chunk = (l&7)^(l>>3)
// == p^(r&7) -> LDS content bit-identical to R10; read side unchanged.
// Loads for tile t+1 issue right after the barrier; compiler's auto
// vmcnt(0)-before-s_barrier provides completion sync. Numerics = R10 exactly
// (fp32 lsum + shfl, pk2p). No setprio (m190: negative in lockstep).

#define Bsz 4
#define Lq 2048
#define Dm 1024
#define NH 16
#define HD 64
// 0.125 * log2(e): folded into Wq/bq so attention uses exp2 directly
#define QSCALE 0.18033688011112042f

typedef unsigned short u16;
typedef __attribute__((ext_vector_type(4))) short bf16x4;
typedef __attribute__((ext_vector_type(8))) short short8;
typedef __attribute__((ext_vector_type(4))) float f32x4;

#define MFMA32(a, b, c) __builtin_amdgcn_mfma_f32_16x16x32_bf16(a, b, c, 0, 0, 0)

typedef __attribute__((address_space(3))) unsigned su32;
typedef __attribute__((address_space(1))) unsigned gu32;
__device__ __forceinline__ void gl_lds16(const u16* g, u16* l) {
  __builtin_amdgcn_global_load_lds((gu32*)(g), (su32*)(l), 16, 0, 0);
}

__device__ __forceinline__ u16 f2b(float x) {
  unsigned u = __builtin_bit_cast(unsigned, x);
  return (u16)((u + 0x7fffu + ((u >> 16) & 1u)) >> 16);  // RNE
}
__device__ __forceinline__ unsigned pk2(float a, float b) {
  return (unsigned)f2b(a) | ((unsigned)f2b(b) << 16);
}
// round-half-up bf16 pair pack via v_perm: lo=bf16(a), hi=bf16(b)
__device__ __forceinline__ unsigned pk2p(float a, float b) {
  return __builtin_amdgcn_perm(__builtin_bit_cast(unsigned, b) + 0x8000u,
                               __builtin_bit_cast(unsigned, a) + 0x8000u, 0x07060302u);
}
__device__ __forceinline__ float fexp2(float x) {
#if __has_builtin(__builtin_amdgcn_exp2f)
  return __builtin_amdgcn_exp2f(x);
#else
  return exp2f(x);
#endif
}

// ---------------- fused triple activation cast fp32 -> bf16 ----------------
__global__ void castk3(const float* __restrict__ q, const float* __restrict__ k,
                       const float* __restrict__ v, u16* __restrict__ dst) {
  const float* s = blockIdx.y == 0 ? q : (blockIdx.y == 1 ? k : v);
  u16* d = dst + (size_t)blockIdx.y * (Bsz * Lq * Dm);
  int i = (blockIdx.x * 256 + threadIdx.x) * 8;
  float4 a = *(const float4*)(s + i);
  float4 b = *(const float4*)(s + i + 4);
  short8 o;
  o[0] = (short)f2b(a.x); o[1] = (short)f2b(a.y);
  o[2] = (short)f2b(a.z); o[3] = (short)f2b(a.w);
  o[4] = (short)f2b(b.x); o[5] = (short)f2b(b.y);
  o[6] = (short)f2b(b.z); o[7] = (short)f2b(b.w);
  *(short8*)(d + i) = o;
}

// fused 4-weight cast, blockIdx.y selects matrix
__global__ void castw(const float* __restrict__ s0, const float* __restrict__ s1,
                      const float* __restrict__ s2, const float* __restrict__ s3,
                      u16* __restrict__ d0, u16* __restrict__ d1,
                      u16* __restrict__ d2, u16* __restrict__ d3) {
  const float* s; u16* d; float sc = 1.0f;
  switch (blockIdx.y) {
    case 0: s = s0; d = d0; sc = QSCALE; break;
    case 1: s = s1; d = d1; break;
    case 2: s = s2; d = d2; break;
    default: s = s3; d = d3; break;
  }
  int i = (blockIdx.x * 256 + threadIdx.x) * 8;
  float4 a = *(const float4*)(s + i);
  float4 b = *(const float4*)(s + i + 4);
  short8 o;
  o[0] = (short)f2b(a.x * sc); o[1] = (short)f2b(a.y * sc);
  o[2] = (short)f2b(a.z * sc); o[3] = (short)f2b(a.w * sc);
  o[4] = (short)f2b(b.x * sc); o[5] = (short)f2b(b.y * sc);
  o[6] = (short)f2b(b.z * sc); o[7] = (short)f2b(b.w * sc);
  *(short8*)(d + i) = o;
}

// ---------------- fused QKV projection GEMM ----------------
// grid (8, 64, 3). z: {q->Qh (scaled), k->Kh, v->Vtg (transposed+permuted)}.
__global__ __launch_bounds__(256) void qkv_gemm(
    const u16* __restrict__ Ab,
    const u16* __restrict__ Wqb, const u16* __restrict__ Wkb, const u16* __restrict__ Wvb,
    const float* __restrict__ bq, const float* __restrict__ bk, const float* __restrict__ bv,
    u16* __restrict__ Qh, u16* __restrict__ Kh, u16* __restrict__ Vtg)
{
  __shared__ __align__(16) u16 As[128 * 32];
  __shared__ __align__(16) u16 Bs[128 * 32];
  const int z = blockIdx.z;
  const u16* A  = Ab + (size_t)z * (Bsz * Lq * Dm);
  const u16* Bt = z == 0 ? Wqb : (z == 1 ? Wkb : Wvb);
  const float* bias = z == 0 ? bq : (z == 1 ? bk : bv);
  const float bscale = z == 0 ? QSCALE : 1.0f;

  const int tid  = threadIdx.x;
  const int lane = tid & 63;
  const int wave = tid >> 6;
  const int quad = lane >> 4;
  const int r16  = lane & 15;
  const int wm   = (wave >> 1) * 64;
  const int wn   = (wave & 1) * 64;
  const int m0   = blockIdx.y * 128;
  const int n0   = blockIdx.x * 128;

  const u16* ga = A  + (size_t)(m0 + wave * 32 + (lane >> 2)) * Dm + (lane & 3) * 8;
  const u16* gb = Bt + (size_t)(n0 + wave * 32 + (lane >> 2)) * Dm + (lane & 3) * 8;
  u16* la = As + wave * 1024;
  u16* lb = Bs + wave * 1024;

  f32x4 acc[4][4] = {};

  for (int k0 = 0; k0 < Dm; k0 += 32) {
    gl_lds16(ga + k0, la);
    gl_lds16(ga + k0 + 16 * Dm, la + 512);
    gl_lds16(gb + k0, lb);
    gl_lds16(gb + k0 + 16 * Dm, lb + 512);
    __syncthreads();

    short8 af[4], bfr[4];
#pragma unroll
    for (int mt = 0; mt < 4; ++mt) af[mt]  = *(const short8*)&As[(wm + mt * 16 + r16) * 32 + quad * 8];
#pragma unroll
    for (int nt = 0; nt < 4; ++nt) bfr[nt] = *(const short8*)&Bs[(wn + nt * 16 + r16) * 32 + quad * 8];
#pragma unroll
    for (int mt = 0; mt < 4; ++mt)
#pragma unroll
      for (int nt = 0; nt < 4; ++nt)
        acc[mt][nt] = MFMA32(af[mt], bfr[nt], acc[mt][nt]);
    __syncthreads();
  }

#pragma unroll
  for (int mt = 0; mt < 4; ++mt) {
#pragma unroll
    for (int nt = 0; nt < 4; ++nt) {
      int n = n0 + wn + nt * 16 + r16;
      float bv_ = bias[n] * bscale;
      if (z == 2) {
        // V: transposed head-split Vtg[bh][d][l'], column-permuted within each
        // 32-block: l' = (l&~31) | q<<3 | w<<2 | j  (q=(l>>2)&3, w=(l>>4)&1)
        // so attention's b128 A-frag slot (quad,i=4w+j) carries the kpos that
        // the P B-frag holds in the same slot.
        int m_base = m0 + wm + mt * 16 + quad * 4;
        int b = m_base >> 11, l0 = m_base & 2047;
        int lp = (l0 & ~31) | (((l0 >> 2) & 3) << 3) | (((l0 >> 4) & 1) << 2);
        int h = n >> 6, d = n & 63;
        u16* dst = Vtg + (((size_t)(b * NH + h)) * HD + d) * Lq + lp;
        uint2 pkd;
        pkd.x = pk2(acc[mt][nt][0] + bv_, acc[mt][nt][1] + bv_);
        pkd.y = pk2(acc[mt][nt][2] + bv_, acc[mt][nt][3] + bv_);
        *(uint2*)dst = pkd;
      } else {
        u16* dst = z == 0 ? Qh : Kh;
#pragma unroll
        for (int j = 0; j < 4; ++j) {
          int m = m0 + wm + mt * 16 + quad * 4 + j;
          int b = m >> 11, l = m & 2047;
          int h = n >> 6,  d = n & 63;
          dst[(((size_t)(b * NH + h)) * Lq + l) * HD + d] = f2b(acc[mt][nt][j] + bv_);
        }
      }
    }
  }
}

// ---------------- Wo GEMM: 128x64 tile, fp32 out ----------------
__global__ __launch_bounds__(256) void gemm_wo(
    const u16* __restrict__ A, const u16* __restrict__ Bt,
    const float* __restrict__ bias, float* __restrict__ C)
{
  __shared__ __align__(16) u16 As[128 * 32];
  __shared__ __align__(16) u16 Bs[64 * 32];
  const int tid  = threadIdx.x;
  const int lane = tid & 63;
  const int wave = tid >> 6;
  const int quad = lane >> 4;
  const int r16  = lane & 15;
  const int wm   = wave * 32;
  const int m0   = blockIdx.y * 128;
  const int n0   = blockIdx.x * 64;

  const u16* ga = A  + (size_t)(m0 + wave * 32 + (lane >> 2)) * Dm + (lane & 3) * 8;
  const u16* gb = Bt + (size_t)(n0 + wave * 16 + (lane >> 2)) * Dm + (lane & 3) * 8;
  u16* la = As + wave * 1024;
  u16* lb = Bs + wave * 512;

  f32x4 acc[2][4] = {};

  for (int k0 = 0; k0 < Dm; k0 += 32) {
    gl_lds16(ga + k0, la);
    gl_lds16(ga + k0 + 16 * Dm, la + 512);
    gl_lds16(gb + k0, lb);
    __syncthreads();

    short8 af[2], bfr[4];
#pragma unroll
    for (int mt = 0; mt < 2; ++mt) af[mt]  = *(const short8*)&As[(wm + mt * 16 + r16) * 32 + quad * 8];
#pragma unroll
    for (int nt = 0; nt < 4; ++nt) bfr[nt] = *(const short8*)&Bs[(nt * 16 + r16) * 32 + quad * 8];
#pragma unroll
    for (int mt = 0; mt < 2; ++mt)
#pragma unroll
      for (int nt = 0; nt < 4; ++nt)
        acc[mt][nt] = MFMA32(af[mt], bfr[nt], acc[mt][nt]);
    __syncthreads();
  }

#pragma unroll
  for (int mt = 0; mt < 2; ++mt) {
#pragma unroll
    for (int nt = 0; nt < 4; ++nt) {
      int n = n0 + nt * 16 + r16;
      float bv = bias[n];
#pragma unroll
      for (int j = 0; j < 4; ++j) {
        int m = m0 + wm + mt * 16 + quad * 4 + j;
        C[(size_t)m * Dm + n] = acc[mt][nt][j] + bv;
      }
    }
  }
}

// ---------------- fused flash attention (S^T form, K=32 PV) ----------------
// Qh (pre-scaled), Kh: [bh][L][HD] bf16. Vtg: [bh][HD][L] bf16, col-permuted.
// Oa: [B*L][D] bf16 row-major. Block: 4 waves x 32 q = 128 q; k-tiles of 64.
// LDS 2-deep double buffer, XOR-swizzled (phys chunk p of row r holds logical
// chunk p^(r&7)), filled by global_load_lds with pre-swizzled global source.
__global__ __launch_bounds__(256) void attn4(
    const u16* __restrict__ Qh, const u16* __restrict__ Kh,
    const u16* __restrict__ Vtg, u16* __restrict__ Oa)
{
  const int bh = blockIdx.y;   // 0..63
  const int qt = blockIdx.x;   // 0..15
  const int tid = threadIdx.x, lane = tid & 63, wave = tid >> 6;
  const int quad = lane >> 4, r16 = lane & 15;

  __shared__ __align__(16) u16 Ks[2][64][64];   // [buf][kpos][d], chunk-swizzled
  __shared__ __align__(16) u16 Vt[2][64][64];   // [buf][d][kpos'] (permuted), chunk-swizzled

  const int qbase = qt * 128 + wave * 32;
  short8 aq[2][2];
#pragma unroll
  for (int qf = 0; qf < 2; ++qf) {
    const size_t qrow = ((size_t)bh * Lq + qbase + qf * 16 + r16) * HD;
    aq[qf][0] = *(const short8*)(Qh + qrow + quad * 8);
    aq[qf][1] = *(const short8*)(Qh + qrow + 32 + quad * 8);
  }

  f32x4 oacc[2][4] = {};
  float lsum[2] = {0.f, 0.f};

  // Async staging geometry: wave w, instr i (0/1), lane l -> LDS elem
  //   w*1024 + i*512 + l*8  (gl_lds writes base + lane*16B linearly)
  // => row r = w*16 + i*8 + (l>>3), phys chunk p = l&7. Swizzled content
  // requires source logical chunk p^(r&7) = (l&7)^(l>>3) (i*8 keeps r&7).
  const int srcc = ((lane & 7) ^ (lane >> 3)) * 8;   // source chunk offset, elems
  const int r0   = wave * 16 + (lane >> 3);          // tile row for instr 0
  const u16* kg0 = Kh  + ((size_t)bh * Lq + r0) * HD + srcc;
  const u16* kg1 = kg0 + 8 * HD;                     // instr 1: row +8
  const u16* vg0 = Vtg + ((size_t)bh * HD + r0) * Lq + srcc;
  const u16* vg1 = vg0 + 8 * Lq;
  u16* ksb = &Ks[0][0][0];
  u16* vtb = &Vt[0][0][0];
  const int ldst = wave * 1024;                      // wave-uniform LDS base, elems

  // prologue: stage tile 0 into buffer 0
  gl_lds16(kg0, ksb + ldst);
  gl_lds16(kg1, ksb + ldst + 512);
  gl_lds16(vg0, vtb + ldst);
  gl_lds16(vg1, vtb + ldst + 512);

  const int sx = r16 & 7;           // read-side swizzle key (rows are 16k+r16)

#pragma unroll 2
  for (int t = 0; t < 32; ++t) {
    // barrier: compiler emits s_waitcnt vmcnt(0) before s_barrier, draining
    // this wave's tile-t loads; barrier gives cross-wave visibility.
    __syncthreads();
    const int cur = (t & 1) * 4096;
    const int nxt = 4096 - cur;
    if (t < 31) {
      // issue tile t+1 into the other buffer (safe: everyone has passed the
      // barrier, so no wave still reads that buffer)
      const size_t ko = (size_t)(t + 1) * (64 * HD);
      const int    vo = (t + 1) * 64;
      gl_lds16(kg0 + ko, ksb + nxt + ldst);
      gl_lds16(kg1 + ko, ksb + nxt + ldst + 512);
      gl_lds16(vg0 + vo, vtb + nxt + ldst);
      gl_lds16(vg1 + vo, vtb + nxt + ldst + 512);
    }

#pragma unroll
    for (int ks = 0; ks < 2; ++ks) {
      // S^T for the two 16-kpos chunks of this 32-window
      f32x4 stq[2][2];
#pragma unroll
      for (int mtl = 0; mtl < 2; ++mtl) {
        const int mt = 2 * ks + mtl;
        short8 kf0 = *(const short8*)(ksb + cur + (mt * 16 + r16) * 64 + ((quad    ) ^ sx) * 8);
        short8 kf1 = *(const short8*)(ksb + cur + (mt * 16 + r16) * 64 + ((quad + 4) ^ sx) * 8);
#pragma unroll
        for (int qf = 0; qf < 2; ++qf) {
          f32x4 zz = {};
          zz = MFMA32(kf0, aq[qf][0], zz);
          zz = MFMA32(kf1, aq[qf][1], zz);
          stq[qf][mtl] = zz;
        }
      }
      // V A-frags for this window (permuted layout -> direct b128)
      short8 vf[4];
#pragma unroll
      for (int nt = 0; nt < 4; ++nt)
        vf[nt] = *(const short8*)(vtb + cur + (nt * 16 + r16) * 64 + ((ks * 4 + quad) ^ sx) * 8);
      // softmax + PV at K=32
#pragma unroll
      for (int qf = 0; qf < 2; ++qf) {
        f32x4 sa = stq[qf][0], sb = stq[qf][1];
        float p0 = fexp2(sa[0]), p1 = fexp2(sa[1]), p2 = fexp2(sa[2]), p3 = fexp2(sa[3]);
        float p4 = fexp2(sb[0]), p5 = fexp2(sb[1]), p6 = fexp2(sb[2]), p7 = fexp2(sb[3]);
        lsum[qf] += ((p0 + p1) + (p2 + p3)) + ((p4 + p5) + (p6 + p7));
        uint4 pu;
        pu.x = pk2p(p0, p1);
        pu.y = pk2p(p2, p3);
        pu.z = pk2p(p4, p5);
        pu.w = pk2p(p6, p7);
        short8 pb = __builtin_bit_cast(short8, pu);
#pragma unroll
        for (int nt = 0; nt < 4; ++nt)
          oacc[qf][nt] = MFMA32(vf[nt], pb, oacc[qf][nt]);
      }
    }
  }

  const int b = bh >> 4, h = bh & 15;
  float linv[2];
#pragma unroll
  for (int qf = 0; qf < 2; ++qf) {
    float r = lsum[qf];
    r += __shfl_xor(r, 16);
    r += __shfl_xor(r, 32);
    linv[qf] = 1.0f / r;
  }
#pragma unroll
  for (int qf = 0; qf < 2; ++qf) {
    int q = qbase + qf * 16 + r16;
    size_t rowb = ((size_t)(b * Lq + q)) * Dm + h * HD;
#pragma unroll
    for (int nt = 0; nt < 4; ++nt) {
      f32x4 o = oacc[qf][nt];
      uint2 pkd;
      pkd.x = pk2(o[0] * linv[qf], o[1] * linv[qf]);
      pkd.y = pk2(o[2] * linv[qf], o[3] * linv[qf]);
      *(uint2*)&Oa[rowb + nt * 16 + quad * 4] = pkd;
    }
  }
}

// ---------------- launcher ----------------
extern "C" void kernel_launch(void* const* d_in, const int* in_sizes, int n_in,
                              void* d_out, int out_size, void* d_ws, size_t ws_size,
                              hipStream_t stream) {
  const float* q  = (const float*)d_in[0];
  const float* k  = (const float*)d_in[1];
  const float* v  = (const float*)d_in[2];
  const float* Wq = (const float*)d_in[3];
  const float* bq = (const float*)d_in[4];
  const float* Wk = (const float*)d_in[5];
  const float* bk = (const float*)d_in[6];
  const float* Wv = (const float*)d_in[7];
  const float* bv = (const float*)d_in[8];
  const float* Wo = (const float*)d_in[9];
  const float* bo = (const float*)d_in[10];

  const int NA = Bsz * Lq * Dm;  // 8388608
  u16* abuf = (u16*)d_ws;            // [3][M][K] activations bf16; later Oa
  u16* Qh   = abuf + (size_t)3 * NA;
  u16* Kh   = Qh   + NA;
  u16* Vtg  = Kh   + NA;
  u16* wqb  = Vtg  + NA;
  u16* wkb  = wqb  + 1048576;
  u16* wvb  = wkb  + 1048576;
  u16* wob  = wvb  + 1048576;

  castw<<<dim3(512, 4), 256, 0, stream>>>(Wq, Wk, Wv, Wo, wqb, wkb, wvb, wob);
  castk3<<<dim3(NA / 2048, 3), 256, 0, stream>>>(q, k, v, abuf);

  qkv_gemm<<<dim3(8, 64, 3), 256, 0, stream>>>(abuf, wqb, wkb, wvb, bq, bk, bv, Qh, Kh, Vtg);

  attn4<<<dim3(Lq / 128, Bsz * NH), 256, 0, stream>>>(Qh, Kh, Vtg, abuf);

  gemm_wo<<<dim3(16, 64), 256, 0, stream>>>(abuf, wob, bo, (float*)d_out);
}

// Round 5
// 355.452 us; speedup vs baseline: 1.0463x; 1.0252x over previous
//
#include <hip/hip_runtime.h>

// MultiHead attention, B=4 L=2048 D=1024 H=16 HD=64.
// R13: attn4 work-per-barrier doubling. Single change vs R12: each wave owns
// 64 q rows (4 qf fragments, was 2), block covers 256 q, grid (8,64)=512
// blocks. Per k-tile iteration a wave now runs 64 MFMAs on the SAME 16 LDS
// b128 reads (K/V frags reused across 4 qf): LDS read traffic halves, the
// barrier/staging cost is amortized 2x, and 4 independent softmax chains
// give intra-wave ILP against exp2/MFMA latency (R10-R12 showed extra waves
// don't hide it; chain-starved per barrier window). Numerics bit-identical
// to R12 per q-row (same op order) -> absmax must stay 1.464844e-3.
// Async gl_lds staging + XOR swizzle + 2-deep dbuf unchanged from R12.

#define Bsz 4
#define Lq 2048
#define Dm 1024
#define NH 16
#define HD 64
// 0.125 * log2(e): folded into Wq/bq so attention uses exp2 directly
#define QSCALE 0.18033688011112042f

typedef unsigned short u16;
typedef __attribute__((ext_vector_type(4))) short bf16x4;
typedef __attribute__((ext_vector_type(8))) short short8;
typedef __attribute__((ext_vector_type(4))) float f32x4;

#define MFMA32(a, b, c) __builtin_amdgcn_mfma_f32_16x16x32_bf16(a, b, c, 0, 0, 0)

typedef __attribute__((address_space(3))) unsigned su32;
typedef __attribute__((address_space(1))) unsigned gu32;
__device__ __forceinline__ void gl_lds16(const u16* g, u16* l) {
  __builtin_amdgcn_global_load_lds((gu32*)(g), (su32*)(l), 16, 0, 0);
}

__device__ __forceinline__ u16 f2b(float x) {
  unsigned u = __builtin_bit_cast(unsigned, x);
  return (u16)((u + 0x7fffu + ((u >> 16) & 1u)) >> 16);  // RNE
}
__device__ __forceinline__ unsigned pk2(float a, float b) {
  return (unsigned)f2b(a) | ((unsigned)f2b(b) << 16);
}
// round-half-up bf16 pair pack via v_perm: lo=bf16(a), hi=bf16(b)
__device__ __forceinline__ unsigned pk2p(float a, float b) {
  return __builtin_amdgcn_perm(__builtin_bit_cast(unsigned, b) + 0x8000u,
                               __builtin_bit_cast(unsigned, a) + 0x8000u, 0x07060302u);
}
__device__ __forceinline__ float fexp2(float x) {
#if __has_builtin(__builtin_amdgcn_exp2f)
  return __builtin_amdgcn_exp2f(x);
#else
  return exp2f(x);
#endif
}

// ---------------- fused triple activation cast fp32 -> bf16 ----------------
__global__ void castk3(const float* __restrict__ q, const float* __restrict__ k,
                       const float* __restrict__ v, u16* __restrict__ dst) {
  const float* s = blockIdx.y == 0 ? q : (blockIdx.y == 1 ? k : v);
  u16* d = dst + (size_t)blockIdx.y * (Bsz * Lq * Dm);
  int i = (blockIdx.x * 256 + threadIdx.x) * 8;
  float4 a = *(const float4*)(s + i);
  float4 b = *(const float4*)(s + i + 4);
  short8 o;
  o[0] = (short)f2b(a.x); o[1] = (short)f2b(a.y);
  o[2] = (short)f2b(a.z); o[3] = (short)f2b(a.w);
  o[4] = (short)f2b(b.x); o[5] = (short)f2b(b.y);
  o[6] = (short)f2b(b.z); o[7] = (short)f2b(b.w);
  *(short8*)(d + i) = o;
}

// fused 4-weight cast, blockIdx.y selects matrix
__global__ void castw(const float* __restrict__ s0, const float* __restrict__ s1,
                      const float* __restrict__ s2, const float* __restrict__ s3,
                      u16* __restrict__ d0, u16* __restrict__ d1,
                      u16* __restrict__ d2, u16* __restrict__ d3) {
  const float* s; u16* d; float sc = 1.0f;
  switch (blockIdx.y) {
    case 0: s = s0; d = d0; sc = QSCALE; break;
    case 1: s = s1; d = d1; break;
    case 2: s = s2; d = d2; break;
    default: s = s3; d = d3; break;
  }
  int i = (blockIdx.x * 256 + threadIdx.x) * 8;
  float4 a = *(const float4*)(s + i);
  float4 b = *(const float4*)(s + i + 4);
  short8 o;
  o[0] = (short)f2b(a.x * sc); o[1] = (short)f2b(a.y * sc);
  o[2] = (short)f2b(a.z * sc); o[3] = (short)f2b(a.w * sc);
  o[4] = (short)f2b(b.x * sc); o[5] = (short)f2b(b.y * sc);
  o[6] = (short)f2b(b.z * sc); o[7] = (short)f2b(b.w * sc);
  *(short8*)(d + i) = o;
}

// ---------------- fused QKV projection GEMM ----------------
// grid (8, 64, 3). z: {q->Qh (scaled), k->Kh, v->Vtg (transposed+permuted)}.
__global__ __launch_bounds__(256) void qkv_gemm(
    const u16* __restrict__ Ab,
    const u16* __restrict__ Wqb, const u16* __restrict__ Wkb, const u16* __restrict__ Wvb,
    const float* __restrict__ bq, const float* __restrict__ bk, const float* __restrict__ bv,
    u16* __restrict__ Qh, u16* __restrict__ Kh, u16* __restrict__ Vtg)
{
  __shared__ __align__(16) u16 As[128 * 32];
  __shared__ __align__(16) u16 Bs[128 * 32];
  const int z = blockIdx.z;
  const u16* A  = Ab + (size_t)z * (Bsz * Lq * Dm);
  const u16* Bt = z == 0 ? Wqb : (z == 1 ? Wkb : Wvb);
  const float* bias = z == 0 ? bq : (z == 1 ? bk : bv);
  const float bscale = z == 0 ? QSCALE : 1.0f;

  const int tid  = threadIdx.x;
  const int lane = tid & 63;
  const int wave = tid >> 6;
  const int quad = lane >> 4;
  const int r16  = lane & 15;
  const int wm   = (wave >> 1) * 64;
  const int wn   = (wave & 1) * 64;
  const int m0   = blockIdx.y * 128;
  const int n0   = blockIdx.x * 128;

  const u16* ga = A  + (size_t)(m0 + wave * 32 + (lane >> 2)) * Dm + (lane & 3) * 8;
  const u16* gb = Bt + (size_t)(n0 + wave * 32 + (lane >> 2)) * Dm + (lane & 3) * 8;
  u16* la = As + wave * 1024;
  u16* lb = Bs + wave * 1024;

  f32x4 acc[4][4] = {};

  for (int k0 = 0; k0 < Dm; k0 += 32) {
    gl_lds16(ga + k0, la);
    gl_lds16(ga + k0 + 16 * Dm, la + 512);
    gl_lds16(gb + k0, lb);
    gl_lds16(gb + k0 + 16 * Dm, lb + 512);
    __syncthreads();

    short8 af[4], bfr[4];
#pragma unroll
    for (int mt = 0; mt < 4; ++mt) af[mt]  = *(const short8*)&As[(wm + mt * 16 + r16) * 32 + quad * 8];
#pragma unroll
    for (int nt = 0; nt < 4; ++nt) bfr[nt] = *(const short8*)&Bs[(wn + nt * 16 + r16) * 32 + quad * 8];
#pragma unroll
    for (int mt = 0; mt < 4; ++mt)
#pragma unroll
      for (int nt = 0; nt < 4; ++nt)
        acc[mt][nt] = MFMA32(af[mt], bfr[nt], acc[mt][nt]);
    __syncthreads();
  }

#pragma unroll
  for (int mt = 0; mt < 4; ++mt) {
#pragma unroll
    for (int nt = 0; nt < 4; ++nt) {
      int n = n0 + wn + nt * 16 + r16;
      float bv_ = bias[n] * bscale;
      if (z == 2) {
        // V: transposed head-split Vtg[bh][d][l'], column-permuted within each
        // 32-block: l' = (l&~31) | q<<3 | w<<2 | j  (q=(l>>2)&3, w=(l>>4)&1)
        // so attention's b128 A-frag slot (quad,i=4w+j) carries the kpos that
        // the P B-frag holds in the same slot.
        int m_base = m0 + wm + mt * 16 + quad * 4;
        int b = m_base >> 11, l0 = m_base & 2047;
        int lp = (l0 & ~31) | (((l0 >> 2) & 3) << 3) | (((l0 >> 4) & 1) << 2);
        int h = n >> 6, d = n & 63;
        u16* dst = Vtg + (((size_t)(b * NH + h)) * HD + d) * Lq + lp;
        uint2 pkd;
        pkd.x = pk2(acc[mt][nt][0] + bv_, acc[mt][nt][1] + bv_);
        pkd.y = pk2(acc[mt][nt][2] + bv_, acc[mt][nt][3] + bv_);
        *(uint2*)dst = pkd;
      } else {
        u16* dst = z == 0 ? Qh : Kh;
#pragma unroll
        for (int j = 0; j < 4; ++j) {
          int m = m0 + wm + mt * 16 + quad * 4 + j;
          int b = m >> 11, l = m & 2047;
          int h = n >> 6,  d = n & 63;
          dst[(((size_t)(b * NH + h)) * Lq + l) * HD + d] = f2b(acc[mt][nt][j] + bv_);
        }
      }
    }
  }
}

// ---------------- Wo GEMM: 128x64 tile, fp32 out ----------------
__global__ __launch_bounds__(256) void gemm_wo(
    const u16* __restrict__ A, const u16* __restrict__ Bt,
    const float* __restrict__ bias, float* __restrict__ C)
{
  __shared__ __align__(16) u16 As[128 * 32];
  __shared__ __align__(16) u16 Bs[64 * 32];
  const int tid  = threadIdx.x;
  const int lane = tid & 63;
  const int wave = tid >> 6;
  const int quad = lane >> 4;
  const int r16  = lane & 15;
  const int wm   = wave * 32;
  const int m0   = blockIdx.y * 128;
  const int n0   = blockIdx.x * 64;

  const u16* ga = A  + (size_t)(m0 + wave * 32 + (lane >> 2)) * Dm + (lane & 3) * 8;
  const u16* gb = Bt + (size_t)(n0 + wave * 16 + (lane >> 2)) * Dm + (lane & 3) * 8;
  u16* la = As + wave * 1024;
  u16* lb = Bs + wave * 512;

  f32x4 acc[2][4] = {};

  for (int k0 = 0; k0 < Dm; k0 += 32) {
    gl_lds16(ga + k0, la);
    gl_lds16(ga + k0 + 16 * Dm, la + 512);
    gl_lds16(gb + k0, lb);
    __syncthreads();

    short8 af[2], bfr[4];
#pragma unroll
    for (int mt = 0; mt < 2; ++mt) af[mt]  = *(const short8*)&As[(wm + mt * 16 + r16) * 32 + quad * 8];
#pragma unroll
    for (int nt = 0; nt < 4; ++nt) bfr[nt] = *(const short8*)&Bs[(nt * 16 + r16) * 32 + quad * 8];
#pragma unroll
    for (int mt = 0; mt < 2; ++mt)
#pragma unroll
      for (int nt = 0; nt < 4; ++nt)
        acc[mt][nt] = MFMA32(af[mt], bfr[nt], acc[mt][nt]);
    __syncthreads();
  }

#pragma unroll
  for (int mt = 0; mt < 2; ++mt) {
#pragma unroll
    for (int nt = 0; nt < 4; ++nt) {
      int n = n0 + nt * 16 + r16;
      float bv = bias[n];
#pragma unroll
      for (int j = 0; j < 4; ++j) {
        int m = m0 + wm + mt * 16 + quad * 4 + j;
        C[(size_t)m * Dm + n] = acc[mt][nt][j] + bv;
      }
    }
  }
}

// ---------------- fused flash attention (S^T form, K=32 PV) ----------------
// Qh (pre-scaled), Kh: [bh][L][HD] bf16. Vtg: [bh][HD][L] bf16, col-permuted.
// Oa: [B*L][D] bf16 row-major. Block: 4 waves x 64 q = 256 q; k-tiles of 64.
// LDS 2-deep double buffer, XOR-swizzled (phys chunk p of row r holds logical
// chunk p^(r&7)), filled by global_load_lds with pre-swizzled global source.
__global__ __launch_bounds__(256) void attn4(
    const u16* __restrict__ Qh, const u16* __restrict__ Kh,
    const u16* __restrict__ Vtg, u16* __restrict__ Oa)
{
  const int bh = blockIdx.y;   // 0..63
  const int qt = blockIdx.x;   // 0..7
  const int tid = threadIdx.x, lane = tid & 63, wave = tid >> 6;
  const int quad = lane >> 4, r16 = lane & 15;

  __shared__ __align__(16) u16 Ks[2][64][64];   // [buf][kpos][d], chunk-swizzled
  __shared__ __align__(16) u16 Vt[2][64][64];   // [buf][d][kpos'] (permuted), chunk-swizzled

  const int qbase = qt * 256 + wave * 64;
  short8 aq[4][2];
#pragma unroll
  for (int qf = 0; qf < 4; ++qf) {
    const size_t qrow = ((size_t)bh * Lq + qbase + qf * 16 + r16) * HD;
    aq[qf][0] = *(const short8*)(Qh + qrow + quad * 8);
    aq[qf][1] = *(const short8*)(Qh + qrow + 32 + quad * 8);
  }

  f32x4 oacc[4][4] = {};
  float lsum[4] = {0.f, 0.f, 0.f, 0.f};

  // Async staging geometry: wave w, instr i (0/1), lane l -> LDS elem
  //   w*1024 + i*512 + l*8  (gl_lds writes base + lane*16B linearly)
  // => row r = w*16 + i*8 + (l>>3), phys chunk p = l&7. Swizzled content
  // requires source logical chunk p^(r&7) = (l&7)^(l>>3) (i*8 keeps r&7).
  const int srcc = ((lane & 7) ^ (lane >> 3)) * 8;   // source chunk offset, elems
  const int r0   = wave * 16 + (lane >> 3);          // tile row for instr 0
  const u16* kg0 = Kh  + ((size_t)bh * Lq + r0) * HD + srcc;
  const u16* kg1 = kg0 + 8 * HD;                     // instr 1: row +8
  const u16* vg0 = Vtg + ((size_t)bh * HD + r0) * Lq + srcc;
  const u16* vg1 = vg0 + 8 * Lq;
  u16* ksb = &Ks[0][0][0];
  u16* vtb = &Vt[0][0][0];
  const int ldst = wave * 1024;                      // wave-uniform LDS base, elems

  // prologue: stage tile 0 into buffer 0
  gl_lds16(kg0, ksb + ldst);
  gl_lds16(kg1, ksb + ldst + 512);
  gl_lds16(vg0, vtb + ldst);
  gl_lds16(vg1, vtb + ldst + 512);

  const int sx = r16 & 7;           // read-side swizzle key (rows are 16k+r16)

#pragma unroll 2
  for (int t = 0; t < 32; ++t) {
    // barrier: compiler emits s_waitcnt vmcnt(0) before s_barrier, draining
    // this wave's tile-t loads; barrier gives cross-wave visibility.
    __syncthreads();
    const int cur = (t & 1) * 4096;
    const int nxt = 4096 - cur;
    if (t < 31) {
      // issue tile t+1 into the other buffer (safe: everyone has passed the
      // barrier, so no wave still reads that buffer)
      const size_t ko = (size_t)(t + 1) * (64 * HD);
      const int    vo = (t + 1) * 64;
      gl_lds16(kg0 + ko, ksb + nxt + ldst);
      gl_lds16(kg1 + ko, ksb + nxt + ldst + 512);
      gl_lds16(vg0 + vo, vtb + nxt + ldst);
      gl_lds16(vg1 + vo, vtb + nxt + ldst + 512);
    }

#pragma unroll
    for (int ks = 0; ks < 2; ++ks) {
      // K fragments for the two 16-kpos chunks of this 32-window (shared
      // across all 4 q fragments)
      short8 kf[2][2];
#pragma unroll
      for (int mtl = 0; mtl < 2; ++mtl) {
        const int mt = 2 * ks + mtl;
        kf[mtl][0] = *(const short8*)(ksb + cur + (mt * 16 + r16) * 64 + ((quad    ) ^ sx) * 8);
        kf[mtl][1] = *(const short8*)(ksb + cur + (mt * 16 + r16) * 64 + ((quad + 4) ^ sx) * 8);
      }
      // V A-frags for this window (permuted layout -> direct b128), shared
      // across all 4 q fragments
      short8 vf[4];
#pragma unroll
      for (int nt = 0; nt < 4; ++nt)
        vf[nt] = *(const short8*)(vtb + cur + (nt * 16 + r16) * 64 + ((ks * 4 + quad) ^ sx) * 8);
      // per-qf: S^T, softmax, PV at K=32 (4 independent chains for ILP)
#pragma unroll
      for (int qf = 0; qf < 4; ++qf) {
        f32x4 sa = {}, sb = {};
        sa = MFMA32(kf[0][0], aq[qf][0], sa);
        sa = MFMA32(kf[0][1], aq[qf][1], sa);
        sb = MFMA32(kf[1][0], aq[qf][0], sb);
        sb = MFMA32(kf[1][1], aq[qf][1], sb);
        float p0 = fexp2(sa[0]), p1 = fexp2(sa[1]), p2 = fexp2(sa[2]), p3 = fexp2(sa[3]);
        float p4 = fexp2(sb[0]), p5 = fexp2(sb[1]), p6 = fexp2(sb[2]), p7 = fexp2(sb[3]);
        lsum[qf] += ((p0 + p1) + (p2 + p3)) + ((p4 + p5) + (p6 + p7));
        uint4 pu;
        pu.x = pk2p(p0, p1);
        pu.y = pk2p(p2, p3);
        pu.z = pk2p(p4, p5);
        pu.w = pk2p(p6, p7);
        short8 pb = __builtin_bit_cast(short8, pu);
#pragma unroll
        for (int nt = 0; nt < 4; ++nt)
          oacc[qf][nt] = MFMA32(vf[nt], pb, oacc[qf][nt]);
      }
    }
  }

  const int b = bh >> 4, h = bh & 15;
  float linv[4];
#pragma unroll
  for (int qf = 0; qf < 4; ++qf) {
    float r = lsum[qf];
    r += __shfl_xor(r, 16);
    r += __shfl_xor(r, 32);
    linv[qf] = 1.0f / r;
  }
#pragma unroll
  for (int qf = 0; qf < 4; ++qf) {
    int q = qbase + qf * 16 + r16;
    size_t rowb = ((size_t)(b * Lq + q)) * Dm + h * HD;
#pragma unroll
    for (int nt = 0; nt < 4; ++nt) {
      f32x4 o = oacc[qf][nt];
      uint2 pkd;
      pkd.x = pk2(o[0] * linv[qf], o[1] * linv[qf]);
      pkd.y = pk2(o[2] * linv[qf], o[3] * linv[qf]);
      *(uint2*)&Oa[rowb + nt * 16 + quad * 4] = pkd;
    }
  }
}

// ---------------- launcher ----------------
extern "C" void kernel_launch(void* const* d_in, const int* in_sizes, int n_in,
                              void* d_out, int out_size, void* d_ws, size_t ws_size,
                              hipStream_t stream) {
  const float* q  = (const float*)d_in[0];
  const float* k  = (const float*)d_in[1];
  const float* v  = (const float*)d_in[2];
  const float* Wq = (const float*)d_in[3];
  const float* bq = (const float*)d_in[4];
  const float* Wk = (const float*)d_in[5];
  const float* bk = (const float*)d_in[6];
  const float* Wv = (const float*)d_in[7];
  const float* bv = (const float*)d_in[8];
  const float* Wo = (const float*)d_in[9];
  const float* bo = (const float*)d_in[10];

  const int NA = Bsz * Lq * Dm;  // 8388608
  u16* abuf = (u16*)d_ws;            // [3][M][K] activations bf16; later Oa
  u16* Qh   = abuf + (size_t)3 * NA;
  u16* Kh   = Qh   + NA;
  u16* Vtg  = Kh   + NA;
  u16* wqb  = Vtg  + NA;
  u16* wkb  = wqb  + 1048576;
  u16* wvb  = wkb  + 1048576;
  u16* wob  = wvb  + 1048576;

  castw<<<dim3(512, 4), 256, 0, stream>>>(Wq, Wk, Wv, Wo, wqb, wkb, wvb, wob);
  castk3<<<dim3(NA / 2048, 3), 256, 0, stream>>>(q, k, v, abuf);

  qkv_gemm<<<dim3(8, 64, 3), 256, 0, stream>>>(abuf, wqb, wkb, wvb, bq, bk, bv, Qh, Kh, Vtg);

  attn4<<<dim3(Lq / 256, Bsz * NH), 256, 0, stream>>>(Qh, Kh, Vtg, abuf);

  gemm_wo<<<dim3(16, 64), 256, 0, stream>>>(abuf, wob, bo, (float*)d_out);
}

// Round 8
// 353.412 us; speedup vs baseline: 1.0523x; 1.0058x over previous
//
#include <hip/hip_runtime.h>

// MultiHead attention, B=4 L=2048 D=1024 H=16 HD=64.
// R16 == R14/R15 resubmitted (both benches were broker infra failures; every
// component of this source has previously executed on HW: R13 structure ran
// at 97us, cvtpk asm ran in R9, ones-MFMA lsum ran+passed in R11).
// attn4 VALU offload on R13's 64q/wave structure (VALU-bound: VALUBusy 51.5
// vs MfmaUtil 30.4 == static 570:310 cyc budget):
// (1) lsum via ones-A MFMA on the packed P B-frag (R11-proven numerically
//     safe, bit-identical absmax there): -56 VALU adds/t + epilogue shfl,
//     +8 MFMA/t on the idle matrix pipe.
// (2) P-pack via v_cvt_pk_bf16_f32 (RTZ, 1 op vs pk2p's 3): -64 instrs/t.
//     Safe ONLY because (1) makes numerator and denominator use identical
//     truncated weights -> RTZ bias cancels exactly in the ratio (R9's
//     failure was the EPILOGUE cvtpk: |O|~3 RTZ err ~1.3e-2 = R9's absmax).
//     Epilogue O pack and all GEMM packs stay RNE (f2b/pk2).
// Everything else identical to R13.

#define Bsz 4
#define Lq 2048
#define Dm 1024
#define NH 16
#define HD 64
// 0.125 * log2(e): folded into Wq/bq so attention uses exp2 directly
#define QSCALE 0.18033688011112042f

typedef unsigned short u16;
typedef __attribute__((ext_vector_type(4))) short bf16x4;
typedef __attribute__((ext_vector_type(8))) short short8;
typedef __attribute__((ext_vector_type(4))) float f32x4;

#define MFMA32(a, b, c) __builtin_amdgcn_mfma_f32_16x16x32_bf16(a, b, c, 0, 0, 0)

typedef __attribute__((address_space(3))) unsigned su32;
typedef __attribute__((address_space(1))) unsigned gu32;
__device__ __forceinline__ void gl_lds16(const u16* g, u16* l) {
  __builtin_amdgcn_global_load_lds((gu32*)(g), (su32*)(l), 16, 0, 0);
}

__device__ __forceinline__ u16 f2b(float x) {
  unsigned u = __builtin_bit_cast(unsigned, x);
  return (u16)((u + 0x7fffu + ((u >> 16) & 1u)) >> 16);  // RNE
}
__device__ __forceinline__ unsigned pk2(float a, float b) {
  return (unsigned)f2b(a) | ((unsigned)f2b(b) << 16);
}
// round-half-up bf16 pair pack via v_perm: lo=bf16(a), hi=bf16(b)
__device__ __forceinline__ unsigned pk2p(float a, float b) {
  return __builtin_amdgcn_perm(__builtin_bit_cast(unsigned, b) + 0x8000u,
                               __builtin_bit_cast(unsigned, a) + 0x8000u, 0x07060302u);
}
// packed bf16 pair, RTZ (single VALU op) — P-weights only, never outputs
__device__ __forceinline__ unsigned cvtpk(float a, float b) {
  unsigned r;
  asm("v_cvt_pk_bf16_f32 %0, %1, %2" : "=v"(r) : "v"(a), "v"(b));
  return r;
}
__device__ __forceinline__ float fexp2(float x) {
#if __has_builtin(__builtin_amdgcn_exp2f)
  return __builtin_amdgcn_exp2f(x);
#else
  return exp2f(x);
#endif
}

// ---------------- fused triple activation cast fp32 -> bf16 ----------------
__global__ void castk3(const float* __restrict__ q, const float* __restrict__ k,
                       const float* __restrict__ v, u16* __restrict__ dst) {
  const float* s = blockIdx.y == 0 ? q : (blockIdx.y == 1 ? k : v);
  u16* d = dst + (size_t)blockIdx.y * (Bsz * Lq * Dm);
  int i = (blockIdx.x * 256 + threadIdx.x) * 8;
  float4 a = *(const float4*)(s + i);
  float4 b = *(const float4*)(s + i + 4);
  short8 o;
  o[0] = (short)f2b(a.x); o[1] = (short)f2b(a.y);
  o[2] = (short)f2b(a.z); o[3] = (short)f2b(a.w);
  o[4] = (short)f2b(b.x); o[5] = (short)f2b(b.y);
  o[6] = (short)f2b(b.z); o[7] = (short)f2b(b.w);
  *(short8*)(d + i) = o;
}

// fused 4-weight cast, blockIdx.y selects matrix
__global__ void castw(const float* __restrict__ s0, const float* __restrict__ s1,
                      const float* __restrict__ s2, const float* __restrict__ s3,
                      u16* __restrict__ d0, u16* __restrict__ d1,
                      u16* __restrict__ d2, u16* __restrict__ d3) {
  const float* s; u16* d; float sc = 1.0f;
  switch (blockIdx.y) {
    case 0: s = s0; d = d0; sc = QSCALE; break;
    case 1: s = s1; d = d1; break;
    case 2: s = s2; d = d2; break;
    default: s = s3; d = d3; break;
  }
  int i = (blockIdx.x * 256 + threadIdx.x) * 8;
  float4 a = *(const float4*)(s + i);
  float4 b = *(const float4*)(s + i + 4);
  short8 o;
  o[0] = (short)f2b(a.x * sc); o[1] = (short)f2b(a.y * sc);
  o[2] = (short)f2b(a.z * sc); o[3] = (short)f2b(a.w * sc);
  o[4] = (short)f2b(b.x * sc); o[5] = (short)f2b(b.y * sc);
  o[6] = (short)f2b(b.z * sc); o[7] = (short)f2b(b.w * sc);
  *(short8*)(d + i) = o;
}

// ---------------- fused QKV projection GEMM ----------------
// grid (8, 64, 3). z: {q->Qh (scaled), k->Kh, v->Vtg (transposed+permuted)}.
__global__ __launch_bounds__(256) void qkv_gemm(
    const u16* __restrict__ Ab,
    const u16* __restrict__ Wqb, const u16* __restrict__ Wkb, const u16* __restrict__ Wvb,
    const float* __restrict__ bq, const float* __restrict__ bk, const float* __restrict__ bv,
    u16* __restrict__ Qh, u16* __restrict__ Kh, u16* __restrict__ Vtg)
{
  __shared__ __align__(16) u16 As[128 * 32];
  __shared__ __align__(16) u16 Bs[128 * 32];
  const int z = blockIdx.z;
  const u16* A  = Ab + (size_t)z * (Bsz * Lq * Dm);
  const u16* Bt = z == 0 ? Wqb : (z == 1 ? Wkb : Wvb);
  const float* bias = z == 0 ? bq : (z == 1 ? bk : bv);
  const float bscale = z == 0 ? QSCALE : 1.0f;

  const int tid  = threadIdx.x;
  const int lane = tid & 63;
  const int wave = tid >> 6;
  const int quad = lane >> 4;
  const int r16  = lane & 15;
  const int wm   = (wave >> 1) * 64;
  const int wn   = (wave & 1) * 64;
  const int m0   = blockIdx.y * 128;
  const int n0   = blockIdx.x * 128;

  const u16* ga = A  + (size_t)(m0 + wave * 32 + (lane >> 2)) * Dm + (lane & 3) * 8;
  const u16* gb = Bt + (size_t)(n0 + wave * 32 + (lane >> 2)) * Dm + (lane & 3) * 8;
  u16* la = As + wave * 1024;
  u16* lb = Bs + wave * 1024;

  f32x4 acc[4][4] = {};

  for (int k0 = 0; k0 < Dm; k0 += 32) {
    gl_lds16(ga + k0, la);
    gl_lds16(ga + k0 + 16 * Dm, la + 512);
    gl_lds16(gb + k0, lb);
    gl_lds16(gb + k0 + 16 * Dm, lb + 512);
    __syncthreads();

    short8 af[4], bfr[4];
#pragma unroll
    for (int mt = 0; mt < 4; ++mt) af[mt]  = *(const short8*)&As[(wm + mt * 16 + r16) * 32 + quad * 8];
#pragma unroll
    for (int nt = 0; nt < 4; ++nt) bfr[nt] = *(const short8*)&Bs[(wn + nt * 16 + r16) * 32 + quad * 8];
#pragma unroll
    for (int mt = 0; mt < 4; ++mt)
#pragma unroll
      for (int nt = 0; nt < 4; ++nt)
        acc[mt][nt] = MFMA32(af[mt], bfr[nt], acc[mt][nt]);
    __syncthreads();
  }

#pragma unroll
  for (int mt = 0; mt < 4; ++mt) {
#pragma unroll
    for (int nt = 0; nt < 4; ++nt) {
      int n = n0 + wn + nt * 16 + r16;
      float bv_ = bias[n] * bscale;
      if (z == 2) {
        // V: transposed head-split Vtg[bh][d][l'], column-permuted within each
        // 32-block: l' = (l&~31) | q<<3 | w<<2 | j  (q=(l>>2)&3, w=(l>>4)&1)
        // so attention's b128 A-frag slot (quad,i=4w+j) carries the kpos that
        // the P B-frag holds in the same slot.
        int m_base = m0 + wm + mt * 16 + quad * 4;
        int b = m_base >> 11, l0 = m_base & 2047;
        int lp = (l0 & ~31) | (((l0 >> 2) & 3) << 3) | (((l0 >> 4) & 1) << 2);
        int h = n >> 6, d = n & 63;
        u16* dst = Vtg + (((size_t)(b * NH + h)) * HD + d) * Lq + lp;
        uint2 pkd;
        pkd.x = pk2(acc[mt][nt][0] + bv_, acc[mt][nt][1] + bv_);
        pkd.y = pk2(acc[mt][nt][2] + bv_, acc[mt][nt][3] + bv_);
        *(uint2*)dst = pkd;
      } else {
        u16* dst = z == 0 ? Qh : Kh;
#pragma unroll
        for (int j = 0; j < 4; ++j) {
          int m = m0 + wm + mt * 16 + quad * 4 + j;
          int b = m >> 11, l = m & 2047;
          int h = n >> 6,  d = n & 63;
          dst[(((size_t)(b * NH + h)) * Lq + l) * HD + d] = f2b(acc[mt][nt][j] + bv_);
        }
      }
    }
  }
}

// ---------------- Wo GEMM: 128x64 tile, fp32 out ----------------
__global__ __launch_bounds__(256) void gemm_wo(
    const u16* __restrict__ A, const u16* __restrict__ Bt,
    const float* __restrict__ bias, float* __restrict__ C)
{
  __shared__ __align__(16) u16 As[128 * 32];
  __shared__ __align__(16) u16 Bs[64 * 32];
  const int tid  = threadIdx.x;
  const int lane = tid & 63;
  const int wave = tid >> 6;
  const int quad = lane >> 4;
  const int r16  = lane & 15;
  const int wm   = wave * 32;
  const int m0   = blockIdx.y * 128;
  const int n0   = blockIdx.x * 64;

  const u16* ga = A  + (size_t)(m0 + wave * 32 + (lane >> 2)) * Dm + (lane & 3) * 8;
  const u16* gb = Bt + (size_t)(n0 + wave * 16 + (lane >> 2)) * Dm + (lane & 3) * 8;
  u16* la = As + wave * 1024;
  u16* lb = Bs + wave * 512;

  f32x4 acc[2][4] = {};

  for (int k0 = 0; k0 < Dm; k0 += 32) {
    gl_lds16(ga + k0, la);
    gl_lds16(ga + k0 + 16 * Dm, la + 512);
    gl_lds16(gb + k0, lb);
    __syncthreads();

    short8 af[2], bfr[4];
#pragma unroll
    for (int mt = 0; mt < 2; ++mt) af[mt]  = *(const short8*)&As[(wm + mt * 16 + r16) * 32 + quad * 8];
#pragma unroll
    for (int nt = 0; nt < 4; ++nt) bfr[nt] = *(const short8*)&Bs[(nt * 16 + r16) * 32 + quad * 8];
#pragma unroll
    for (int mt = 0; mt < 2; ++mt)
#pragma unroll
      for (int nt = 0; nt < 4; ++nt)
        acc[mt][nt] = MFMA32(af[mt], bfr[nt], acc[mt][nt]);
    __syncthreads();
  }

#pragma unroll
  for (int mt = 0; mt < 2; ++mt) {
#pragma unroll
    for (int nt = 0; nt < 4; ++nt) {
      int n = n0 + nt * 16 + r16;
      float bv = bias[n];
#pragma unroll
      for (int j = 0; j < 4; ++j) {
        int m = m0 + wm + mt * 16 + quad * 4 + j;
        C[(size_t)m * Dm + n] = acc[mt][nt][j] + bv;
      }
    }
  }
}

// ---------------- fused flash attention (S^T form, K=32 PV) ----------------
// Qh (pre-scaled), Kh: [bh][L][HD] bf16. Vtg: [bh][HD][L] bf16, col-permuted.
// Oa: [B*L][D] bf16 row-major. Block: 4 waves x 64 q = 256 q; k-tiles of 64.
// LDS 2-deep double buffer, XOR-swizzled (phys chunk p of row r holds logical
// chunk p^(r&7)), filled by global_load_lds with pre-swizzled global source.
__global__ __launch_bounds__(256) void attn4(
    const u16* __restrict__ Qh, const u16* __restrict__ Kh,
    const u16* __restrict__ Vtg, u16* __restrict__ Oa)
{
  const int bh = blockIdx.y;   // 0..63
  const int qt = blockIdx.x;   // 0..7
  const int tid = threadIdx.x, lane = tid & 63, wave = tid >> 6;
  const int quad = lane >> 4, r16 = lane & 15;

  __shared__ __align__(16) u16 Ks[2][64][64];   // [buf][kpos][d], chunk-swizzled
  __shared__ __align__(16) u16 Vt[2][64][64];   // [buf][d][kpos'] (permuted), chunk-swizzled

  const int qbase = qt * 256 + wave * 64;
  short8 aq[4][2];
#pragma unroll
  for (int qf = 0; qf < 4; ++qf) {
    const size_t qrow = ((size_t)bh * Lq + qbase + qf * 16 + r16) * HD;
    aq[qf][0] = *(const short8*)(Qh + qrow + quad * 8);
    aq[qf][1] = *(const short8*)(Qh + qrow + 32 + quad * 8);
  }

  const short8 ones8 = {0x3F80, 0x3F80, 0x3F80, 0x3F80, 0x3F80, 0x3F80, 0x3F80, 0x3F80};

  f32x4 oacc[4][4] = {};
  f32x4 lacc[4] = {};   // ones*P: every row = column sum of P; col = r16 = own q

  // Async staging geometry: wave w, instr i (0/1), lane l -> LDS elem
  //   w*1024 + i*512 + l*8  (gl_lds writes base + lane*16B linearly)
  // => row r = w*16 + i*8 + (l>>3), phys chunk p = l&7. Swizzled content
  // requires source logical chunk p^(r&7) = (l&7)^(l>>3) (i*8 keeps r&7).
  const int srcc = ((lane & 7) ^ (lane >> 3)) * 8;   // source chunk offset, elems
  const int r0   = wave * 16 + (lane >> 3);          // tile row for instr 0
  const u16* kg0 = Kh  + ((size_t)bh * Lq + r0) * HD + srcc;
  const u16* kg1 = kg0 + 8 * HD;                     // instr 1: row +8
  const u16* vg0 = Vtg + ((size_t)bh * HD + r0) * Lq + srcc;
  const u16* vg1 = vg0 + 8 * Lq;
  u16* ksb = &Ks[0][0][0];
  u16* vtb = &Vt[0][0][0];
  const int ldst = wave * 1024;                      // wave-uniform LDS base, elems

  // prologue: stage tile 0 into buffer 0
  gl_lds16(kg0, ksb + ldst);
  gl_lds16(kg1, ksb + ldst + 512);
  gl_lds16(vg0, vtb + ldst);
  gl_lds16(vg1, vtb + ldst + 512);

  const int sx = r16 & 7;           // read-side swizzle key (rows are 16k+r16)

#pragma unroll 2
  for (int t = 0; t < 32; ++t) {
    // barrier: compiler emits s_waitcnt vmcnt(0) before s_barrier, draining
    // this wave's tile-t loads; barrier gives cross-wave visibility.
    __syncthreads();
    const int cur = (t & 1) * 4096;
    const int nxt = 4096 - cur;
    if (t < 31) {
      // issue tile t+1 into the other buffer (safe: everyone has passed the
      // barrier, so no wave still reads that buffer)
      const size_t ko = (size_t)(t + 1) * (64 * HD);
      const int    vo = (t + 1) * 64;
      gl_lds16(kg0 + ko, ksb + nxt + ldst);
      gl_lds16(kg1 + ko, ksb + nxt + ldst + 512);
      gl_lds16(vg0 + vo, vtb + nxt + ldst);
      gl_lds16(vg1 + vo, vtb + nxt + ldst + 512);
    }

#pragma unroll
    for (int ks = 0; ks < 2; ++ks) {
      // K fragments for the two 16-kpos chunks of this 32-window (shared
      // across all 4 q fragments)
      short8 kf[2][2];
#pragma unroll
      for (int mtl = 0; mtl < 2; ++mtl) {
        const int mt = 2 * ks + mtl;
        kf[mtl][0] = *(const short8*)(ksb + cur + (mt * 16 + r16) * 64 + ((quad    ) ^ sx) * 8);
        kf[mtl][1] = *(const short8*)(ksb + cur + (mt * 16 + r16) * 64 + ((quad + 4) ^ sx) * 8);
      }
      // V A-frags for this window (permuted layout -> direct b128), shared
      // across all 4 q fragments
      short8 vf[4];
#pragma unroll
      for (int nt = 0; nt < 4; ++nt)
        vf[nt] = *(const short8*)(vtb + cur + (nt * 16 + r16) * 64 + ((ks * 4 + quad) ^ sx) * 8);
      // per-qf: S^T, softmax, PV at K=32 (4 independent chains for ILP).
      // P packed RTZ; lsum MFMA-summed from the SAME truncated P, so the
      // RTZ bias cancels exactly in the final O = num/den ratio.
#pragma unroll
      for (int qf = 0; qf < 4; ++qf) {
        f32x4 sa = {}, sb = {};
        sa = MFMA32(kf[0][0], aq[qf][0], sa);
        sa = MFMA32(kf[0][1], aq[qf][1], sa);
        sb = MFMA32(kf[1][0], aq[qf][0], sb);
        sb = MFMA32(kf[1][1], aq[qf][1], sb);
        uint4 pu;
        pu.x = cvtpk(fexp2(sa[0]), fexp2(sa[1]));
        pu.y = cvtpk(fexp2(sa[2]), fexp2(sa[3]));
        pu.z = cvtpk(fexp2(sb[0]), fexp2(sb[1]));
        pu.w = cvtpk(fexp2(sb[2]), fexp2(sb[3]));
        short8 pb = __builtin_bit_cast(short8, pu);
        lacc[qf] = MFMA32(ones8, pb, lacc[qf]);
#pragma unroll
        for (int nt = 0; nt < 4; ++nt)
          oacc[qf][nt] = MFMA32(vf[nt], pb, oacc[qf][nt]);
      }
    }
  }

  const int b = bh >> 4, h = bh & 15;
  // lacc: ones*P rows all equal the P column-sum; col = r16 = this lane's q
  // in the epilogue mapping below -> no cross-lane reduction needed.
  float linv[4];
#pragma unroll
  for (int qf = 0; qf < 4; ++qf) linv[qf] = 1.0f / lacc[qf][0];
#pragma unroll
  for (int qf = 0; qf < 4; ++qf) {
    int q = qbase + qf * 16 + r16;
    size_t rowb = ((size_t)(b * Lq + q)) * Dm + h * HD;
#pragma unroll
    for (int nt = 0; nt < 4; ++nt) {
      f32x4 o = oacc[qf][nt];
      uint2 pkd;
      pkd.x = pk2(o[0] * linv[qf], o[1] * linv[qf]);
      pkd.y = pk2(o[2] * linv[qf], o[3] * linv[qf]);
      *(uint2*)&Oa[rowb + nt * 16 + quad * 4] = pkd;
    }
  }
}

// ---------------- launcher ----------------
extern "C" void kernel_launch(void* const* d_in, const int* in_sizes, int n_in,
                              void* d_out, int out_size, void* d_ws, size_t ws_size,
                              hipStream_t stream) {
  const float* q  = (const float*)d_in[0];
  const float* k  = (const float*)d_in[1];
  const float* v  = (const float*)d_in[2];
  const float* Wq = (const float*)d_in[3];
  const float* bq = (const float*)d_in[4];
  const float* Wk = (const float*)d_in[5];
  const float* bk = (const float*)d_in[6];
  const float* Wv = (const float*)d_in[7];
  const float* bv = (const float*)d_in[8];
  const float* Wo = (const float*)d_in[9];
  const float* bo = (const float*)d_in[10];

  const int NA = Bsz * Lq * Dm;  // 8388608
  u16* abuf = (u16*)d_ws;            // [3][M][K] activations bf16; later Oa
  u16* Qh   = abuf + (size_t)3 * NA;
  u16* Kh   = Qh   + NA;
  u16* Vtg  = Kh   + NA;
  u16* wqb  = Vtg  + NA;
  u16* wkb  = wqb  + 1048576;
  u16* wvb  = wkb  + 1048576;
  u16* wob  = wvb  + 1048576;

  castw<<<dim3(512, 4), 256, 0, stream>>>(Wq, Wk, Wv, Wo, wqb, wkb, wvb, wob);
  castk3<<<dim3(NA / 2048, 3), 256, 0, stream>>>(q, k, v, abuf);

  qkv_gemm<<<dim3(8, 64, 3), 256, 0, stream>>>(abuf, wqb, wkb, wvb, bq, bk, bv, Qh, Kh, Vtg);

  attn4<<<dim3(Lq / 256, Bsz * NH), 256, 0, stream>>>(Qh, Kh, Vtg, abuf);

  gemm_wo<<<dim3(16, 64), 256, 0, stream>>>(abuf, wob, bo, (float*)d_out);
}

// Round 9
// 351.770 us; speedup vs baseline: 1.0572x; 1.0047x over previous
//
#include <hip/hip_runtime.h>

// MultiHead attention, B=4 L=2048 D=1024 H=16 HD=64.
// R17: qkv_gemm restructure (top dispatch, 88.5us, 582 TF, 6.29M LDS bank
// conflicts, 64 barriers/block at BK=32 -> barrier-drain-bound per m97):
// (1) BK 32->64: 32 K-steps -> 16, barrier count halves, 32 MFMA/wave per
//     window. LDS 32KB (As/Bs [128][64]).
// (2) XOR-swizzled LDS via attn4's HW-proven geometry: gl_lds source chunk
//     (lane&7)^(lane>>3), read chunk (kk*4+quad)^(r16&7) — the exact pattern
//     that took attn4's conflicts 8.39M -> 0 (R10).
// MFMA accumulation order per acc unchanged (k=0,32,64,... preserved via kk
// inner loop) -> absmax must stay bit-identical 1.464844e-3.
// attn4 (R16: VALU offload via ones-MFMA lsum + RTZ cvtpk P-pack, <88us),
// gemm_wo, casts, launcher unchanged.

#define Bsz 4
#define Lq 2048
#define Dm 1024
#define NH 16
#define HD 64
// 0.125 * log2(e): folded into Wq/bq so attention uses exp2 directly
#define QSCALE 0.18033688011112042f

typedef unsigned short u16;
typedef __attribute__((ext_vector_type(4))) short bf16x4;
typedef __attribute__((ext_vector_type(8))) short short8;
typedef __attribute__((ext_vector_type(4))) float f32x4;

#define MFMA32(a, b, c) __builtin_amdgcn_mfma_f32_16x16x32_bf16(a, b, c, 0, 0, 0)

typedef __attribute__((address_space(3))) unsigned su32;
typedef __attribute__((address_space(1))) unsigned gu32;
__device__ __forceinline__ void gl_lds16(const u16* g, u16* l) {
  __builtin_amdgcn_global_load_lds((gu32*)(g), (su32*)(l), 16, 0, 0);
}

__device__ __forceinline__ u16 f2b(float x) {
  unsigned u = __builtin_bit_cast(unsigned, x);
  return (u16)((u + 0x7fffu + ((u >> 16) & 1u)) >> 16);  // RNE
}
__device__ __forceinline__ unsigned pk2(float a, float b) {
  return (unsigned)f2b(a) | ((unsigned)f2b(b) << 16);
}
// round-half-up bf16 pair pack via v_perm: lo=bf16(a), hi=bf16(b)
__device__ __forceinline__ unsigned pk2p(float a, float b) {
  return __builtin_amdgcn_perm(__builtin_bit_cast(unsigned, b) + 0x8000u,
                               __builtin_bit_cast(unsigned, a) + 0x8000u, 0x07060302u);
}
// packed bf16 pair, RTZ (single VALU op) — P-weights only, never outputs
__device__ __forceinline__ unsigned cvtpk(float a, float b) {
  unsigned r;
  asm("v_cvt_pk_bf16_f32 %0, %1, %2" : "=v"(r) : "v"(a), "v"(b));
  return r;
}
__device__ __forceinline__ float fexp2(float x) {
#if __has_builtin(__builtin_amdgcn_exp2f)
  return __builtin_amdgcn_exp2f(x);
#else
  return exp2f(x);
#endif
}

// ---------------- fused triple activation cast fp32 -> bf16 ----------------
__global__ void castk3(const float* __restrict__ q, const float* __restrict__ k,
                       const float* __restrict__ v, u16* __restrict__ dst) {
  const float* s = blockIdx.y == 0 ? q : (blockIdx.y == 1 ? k : v);
  u16* d = dst + (size_t)blockIdx.y * (Bsz * Lq * Dm);
  int i = (blockIdx.x * 256 + threadIdx.x) * 8;
  float4 a = *(const float4*)(s + i);
  float4 b = *(const float4*)(s + i + 4);
  short8 o;
  o[0] = (short)f2b(a.x); o[1] = (short)f2b(a.y);
  o[2] = (short)f2b(a.z); o[3] = (short)f2b(a.w);
  o[4] = (short)f2b(b.x); o[5] = (short)f2b(b.y);
  o[6] = (short)f2b(b.z); o[7] = (short)f2b(b.w);
  *(short8*)(d + i) = o;
}

// fused 4-weight cast, blockIdx.y selects matrix
__global__ void castw(const float* __restrict__ s0, const float* __restrict__ s1,
                      const float* __restrict__ s2, const float* __restrict__ s3,
                      u16* __restrict__ d0, u16* __restrict__ d1,
                      u16* __restrict__ d2, u16* __restrict__ d3) {
  const float* s; u16* d; float sc = 1.0f;
  switch (blockIdx.y) {
    case 0: s = s0; d = d0; sc = QSCALE; break;
    case 1: s = s1; d = d1; break;
    case 2: s = s2; d = d2; break;
    default: s = s3; d = d3; break;
  }
  int i = (blockIdx.x * 256 + threadIdx.x) * 8;
  float4 a = *(const float4*)(s + i);
  float4 b = *(const float4*)(s + i + 4);
  short8 o;
  o[0] = (short)f2b(a.x * sc); o[1] = (short)f2b(a.y * sc);
  o[2] = (short)f2b(a.z * sc); o[3] = (short)f2b(a.w * sc);
  o[4] = (short)f2b(b.x * sc); o[5] = (short)f2b(b.y * sc);
  o[6] = (short)f2b(b.z * sc); o[7] = (short)f2b(b.w * sc);
  *(short8*)(d + i) = o;
}

// ---------------- fused QKV projection GEMM ----------------
// grid (8, 64, 3). z: {q->Qh (scaled), k->Kh, v->Vtg (transposed+permuted)}.
// BK=64, XOR-swizzled LDS (attn4 geometry), 2 barriers per K-step, 16 steps.
__global__ __launch_bounds__(256) void qkv_gemm(
    const u16* __restrict__ Ab,
    const u16* __restrict__ Wqb, const u16* __restrict__ Wkb, const u16* __restrict__ Wvb,
    const float* __restrict__ bq, const float* __restrict__ bk, const float* __restrict__ bv,
    u16* __restrict__ Qh, u16* __restrict__ Kh, u16* __restrict__ Vtg)
{
  __shared__ __align__(16) u16 As[128 * 64];   // [row][64], chunk-swizzled
  __shared__ __align__(16) u16 Bs[128 * 64];
  const int z = blockIdx.z;
  const u16* A  = Ab + (size_t)z * (Bsz * Lq * Dm);
  const u16* Bt = z == 0 ? Wqb : (z == 1 ? Wkb : Wvb);
  const float* bias = z == 0 ? bq : (z == 1 ? bk : bv);
  const float bscale = z == 0 ? QSCALE : 1.0f;

  const int tid  = threadIdx.x;
  const int lane = tid & 63;
  const int wave = tid >> 6;
  const int quad = lane >> 4;
  const int r16  = lane & 15;
  const int wm   = (wave >> 1) * 64;
  const int wn   = (wave & 1) * 64;
  const int m0   = blockIdx.y * 128;
  const int n0   = blockIdx.x * 128;

  // Staging (attn4 geometry): wave stages rows [wave*32, wave*32+32) of each
  // tile in 4 gl_lds instrs of 8 rows. Instr i, lane l -> LDS elem
  //   wave*2048 + i*512 + l*8  (= row (wave*32+i*8+(l>>3)) * 64 + (l&7)*8)
  // phys chunk p = l&7, row&7 = l>>3 -> source logical chunk = (l&7)^(l>>3).
  const int srcc = ((lane & 7) ^ (lane >> 3)) * 8;   // source chunk offset, elems
  const int r0   = wave * 32 + (lane >> 3);          // tile row for instr 0
  const u16* ga = A  + (size_t)(m0 + r0) * Dm + srcc;
  const u16* gb = Bt + (size_t)(n0 + r0) * Dm + srcc;
  u16* la = As + wave * 2048;
  u16* lb = Bs + wave * 2048;

  f32x4 acc[4][4] = {};
  const int sx = r16 & 7;   // read-side swizzle key (read rows are 16k+r16)

  for (int k0 = 0; k0 < Dm; k0 += 64) {
#pragma unroll
    for (int i = 0; i < 4; ++i) {
      gl_lds16(ga + k0 + (size_t)(8 * i) * Dm, la + i * 512);
      gl_lds16(gb + k0 + (size_t)(8 * i) * Dm, lb + i * 512);
    }
    __syncthreads();

    short8 af[4][2], bfr[4][2];
#pragma unroll
    for (int mt = 0; mt < 4; ++mt)
#pragma unroll
      for (int kk = 0; kk < 2; ++kk)
        af[mt][kk] = *(const short8*)&As[(wm + mt * 16 + r16) * 64 + ((kk * 4 + quad) ^ sx) * 8];
#pragma unroll
    for (int nt = 0; nt < 4; ++nt)
#pragma unroll
      for (int kk = 0; kk < 2; ++kk)
        bfr[nt][kk] = *(const short8*)&Bs[(wn + nt * 16 + r16) * 64 + ((kk * 4 + quad) ^ sx) * 8];
    // kk outer so each acc sees k in increasing order (bit-identical to BK=32)
#pragma unroll
    for (int kk = 0; kk < 2; ++kk)
#pragma unroll
      for (int mt = 0; mt < 4; ++mt)
#pragma unroll
        for (int nt = 0; nt < 4; ++nt)
          acc[mt][nt] = MFMA32(af[mt][kk], bfr[nt][kk], acc[mt][nt]);
    __syncthreads();
  }

#pragma unroll
  for (int mt = 0; mt < 4; ++mt) {
#pragma unroll
    for (int nt = 0; nt < 4; ++nt) {
      int n = n0 + wn + nt * 16 + r16;
      float bv_ = bias[n] * bscale;
      if (z == 2) {
        // V: transposed head-split Vtg[bh][d][l'], column-permuted within each
        // 32-block: l' = (l&~31) | q<<3 | w<<2 | j  (q=(l>>2)&3, w=(l>>4)&1)
        // so attention's b128 A-frag slot (quad,i=4w+j) carries the kpos that
        // the P B-frag holds in the same slot.
        int m_base = m0 + wm + mt * 16 + quad * 4;
        int b = m_base >> 11, l0 = m_base & 2047;
        int lp = (l0 & ~31) | (((l0 >> 2) & 3) << 3) | (((l0 >> 4) & 1) << 2);
        int h = n >> 6, d = n & 63;
        u16* dst = Vtg + (((size_t)(b * NH + h)) * HD + d) * Lq + lp;
        uint2 pkd;
        pkd.x = pk2(acc[mt][nt][0] + bv_, acc[mt][nt][1] + bv_);
        pkd.y = pk2(acc[mt][nt][2] + bv_, acc[mt][nt][3] + bv_);
        *(uint2*)dst = pkd;
      } else {
        u16* dst = z == 0 ? Qh : Kh;
#pragma unroll
        for (int j = 0; j < 4; ++j) {
          int m = m0 + wm + mt * 16 + quad * 4 + j;
          int b = m >> 11, l = m & 2047;
          int h = n >> 6,  d = n & 63;
          dst[(((size_t)(b * NH + h)) * Lq + l) * HD + d] = f2b(acc[mt][nt][j] + bv_);
        }
      }
    }
  }
}

// ---------------- Wo GEMM: 128x64 tile, fp32 out ----------------
__global__ __launch_bounds__(256) void gemm_wo(
    const u16* __restrict__ A, const u16* __restrict__ Bt,
    const float* __restrict__ bias, float* __restrict__ C)
{
  __shared__ __align__(16) u16 As[128 * 32];
  __shared__ __align__(16) u16 Bs[64 * 32];
  const int tid  = threadIdx.x;
  const int lane = tid & 63;
  const int wave = tid >> 6;
  const int quad = lane >> 4;
  const int r16  = lane & 15;
  const int wm   = wave * 32;
  const int m0   = blockIdx.y * 128;
  const int n0   = blockIdx.x * 64;

  const u16* ga = A  + (size_t)(m0 + wave * 32 + (lane >> 2)) * Dm + (lane & 3) * 8;
  const u16* gb = Bt + (size_t)(n0 + wave * 16 + (lane >> 2)) * Dm + (lane & 3) * 8;
  u16* la = As + wave * 1024;
  u16* lb = Bs + wave * 512;

  f32x4 acc[2][4] = {};

  for (int k0 = 0; k0 < Dm; k0 += 32) {
    gl_lds16(ga + k0, la);
    gl_lds16(ga + k0 + 16 * Dm, la + 512);
    gl_lds16(gb + k0, lb);
    __syncthreads();

    short8 af[2], bfr[4];
#pragma unroll
    for (int mt = 0; mt < 2; ++mt) af[mt]  = *(const short8*)&As[(wm + mt * 16 + r16) * 32 + quad * 8];
#pragma unroll
    for (int nt = 0; nt < 4; ++nt) bfr[nt] = *(const short8*)&Bs[(nt * 16 + r16) * 32 + quad * 8];
#pragma unroll
    for (int mt = 0; mt < 2; ++mt)
#pragma unroll
      for (int nt = 0; nt < 4; ++nt)
        acc[mt][nt] = MFMA32(af[mt], bfr[nt], acc[mt][nt]);
    __syncthreads();
  }

#pragma unroll
  for (int mt = 0; mt < 2; ++mt) {
#pragma unroll
    for (int nt = 0; nt < 4; ++nt) {
      int n = n0 + nt * 16 + r16;
      float bv = bias[n];
#pragma unroll
      for (int j = 0; j < 4; ++j) {
        int m = m0 + wm + mt * 16 + quad * 4 + j;
        C[(size_t)m * Dm + n] = acc[mt][nt][j] + bv;
      }
    }
  }
}

// ---------------- fused flash attention (S^T form, K=32 PV) ----------------
// Qh (pre-scaled), Kh: [bh][L][HD] bf16. Vtg: [bh][HD][L] bf16, col-permuted.
// Oa: [B*L][D] bf16 row-major. Block: 4 waves x 64 q = 256 q; k-tiles of 64.
// LDS 2-deep double buffer, XOR-swizzled (phys chunk p of row r holds logical
// chunk p^(r&7)), filled by global_load_lds with pre-swizzled global source.
__global__ __launch_bounds__(256) void attn4(
    const u16* __restrict__ Qh, const u16* __restrict__ Kh,
    const u16* __restrict__ Vtg, u16* __restrict__ Oa)
{
  const int bh = blockIdx.y;   // 0..63
  const int qt = blockIdx.x;   // 0..7
  const int tid = threadIdx.x, lane = tid & 63, wave = tid >> 6;
  const int quad = lane >> 4, r16 = lane & 15;

  __shared__ __align__(16) u16 Ks[2][64][64];   // [buf][kpos][d], chunk-swizzled
  __shared__ __align__(16) u16 Vt[2][64][64];   // [buf][d][kpos'] (permuted), chunk-swizzled

  const int qbase = qt * 256 + wave * 64;
  short8 aq[4][2];
#pragma unroll
  for (int qf = 0; qf < 4; ++qf) {
    const size_t qrow = ((size_t)bh * Lq + qbase + qf * 16 + r16) * HD;
    aq[qf][0] = *(const short8*)(Qh + qrow + quad * 8);
    aq[qf][1] = *(const short8*)(Qh + qrow + 32 + quad * 8);
  }

  const short8 ones8 = {0x3F80, 0x3F80, 0x3F80, 0x3F80, 0x3F80, 0x3F80, 0x3F80, 0x3F80};

  f32x4 oacc[4][4] = {};
  f32x4 lacc[4] = {};   // ones*P: every row = column sum of P; col = r16 = own q

  // Async staging geometry: wave w, instr i (0/1), lane l -> LDS elem
  //   w*1024 + i*512 + l*8  (gl_lds writes base + lane*16B linearly)
  // => row r = w*16 + i*8 + (l>>3), phys chunk p = l&7. Swizzled content
  // requires source logical chunk p^(r&7) = (l&7)^(l>>3) (i*8 keeps r&7).
  const int srcc = ((lane & 7) ^ (lane >> 3)) * 8;   // source chunk offset, elems
  const int r0   = wave * 16 + (lane >> 3);          // tile row for instr 0
  const u16* kg0 = Kh  + ((size_t)bh * Lq + r0) * HD + srcc;
  const u16* kg1 = kg0 + 8 * HD;                     // instr 1: row +8
  const u16* vg0 = Vtg + ((size_t)bh * HD + r0) * Lq + srcc;
  const u16* vg1 = vg0 + 8 * Lq;
  u16* ksb = &Ks[0][0][0];
  u16* vtb = &Vt[0][0][0];
  const int ldst = wave * 1024;                      // wave-uniform LDS base, elems

  // prologue: stage tile 0 into buffer 0
  gl_lds16(kg0, ksb + ldst);
  gl_lds16(kg1, ksb + ldst + 512);
  gl_lds16(vg0, vtb + ldst);
  gl_lds16(vg1, vtb + ldst + 512);

  const int sx = r16 & 7;           // read-side swizzle key (rows are 16k+r16)

#pragma unroll 2
  for (int t = 0; t < 32; ++t) {
    // barrier: compiler emits s_waitcnt vmcnt(0) before s_barrier, draining
    // this wave's tile-t loads; barrier gives cross-wave visibility.
    __syncthreads();
    const int cur = (t & 1) * 4096;
    const int nxt = 4096 - cur;
    if (t < 31) {
      // issue tile t+1 into the other buffer (safe: everyone has passed the
      // barrier, so no wave still reads that buffer)
      const size_t ko = (size_t)(t + 1) * (64 * HD);
      const int    vo = (t + 1) * 64;
      gl_lds16(kg0 + ko, ksb + nxt + ldst);
      gl_lds16(kg1 + ko, ksb + nxt + ldst + 512);
      gl_lds16(vg0 + vo, vtb + nxt + ldst);
      gl_lds16(vg1 + vo, vtb + nxt + ldst + 512);
    }

#pragma unroll
    for (int ks = 0; ks < 2; ++ks) {
      // K fragments for the two 16-kpos chunks of this 32-window (shared
      // across all 4 q fragments)
      short8 kf[2][2];
#pragma unroll
      for (int mtl = 0; mtl < 2; ++mtl) {
        const int mt = 2 * ks + mtl;
        kf[mtl][0] = *(const short8*)(ksb + cur + (mt * 16 + r16) * 64 + ((quad    ) ^ sx) * 8);
        kf[mtl][1] = *(const short8*)(ksb + cur + (mt * 16 + r16) * 64 + ((quad + 4) ^ sx) * 8);
      }
      // V A-frags for this window (permuted layout -> direct b128), shared
      // across all 4 q fragments
      short8 vf[4];
#pragma unroll
      for (int nt = 0; nt < 4; ++nt)
        vf[nt] = *(const short8*)(vtb + cur + (nt * 16 + r16) * 64 + ((ks * 4 + quad) ^ sx) * 8);
      // per-qf: S^T, softmax, PV at K=32 (4 independent chains for ILP).
      // P packed RTZ; lsum MFMA-summed from the SAME truncated P, so the
      // RTZ bias cancels exactly in the final O = num/den ratio.
#pragma unroll
      for (int qf = 0; qf < 4; ++qf) {
        f32x4 sa = {}, sb = {};
        sa = MFMA32(kf[0][0], aq[qf][0], sa);
        sa = MFMA32(kf[0][1], aq[qf][1], sa);
        sb = MFMA32(kf[1][0], aq[qf][0], sb);
        sb = MFMA32(kf[1][1], aq[qf][1], sb);
        uint4 pu;
        pu.x = cvtpk(fexp2(sa[0]), fexp2(sa[1]));
        pu.y = cvtpk(fexp2(sa[2]), fexp2(sa[3]));
        pu.z = cvtpk(fexp2(sb[0]), fexp2(sb[1]));
        pu.w = cvtpk(fexp2(sb[2]), fexp2(sb[3]));
        short8 pb = __builtin_bit_cast(short8, pu);
        lacc[qf] = MFMA32(ones8, pb, lacc[qf]);
#pragma unroll
        for (int nt = 0; nt < 4; ++nt)
          oacc[qf][nt] = MFMA32(vf[nt], pb, oacc[qf][nt]);
      }
    }
  }

  const int b = bh >> 4, h = bh & 15;
  // lacc: ones*P rows all equal the P column-sum; col = r16 = this lane's q
  // in the epilogue mapping below -> no cross-lane reduction needed.
  float linv[4];
#pragma unroll
  for (int qf = 0; qf < 4; ++qf) linv[qf] = 1.0f / lacc[qf][0];
#pragma unroll
  for (int qf = 0; qf < 4; ++qf) {
    int q = qbase + qf * 16 + r16;
    size_t rowb = ((size_t)(b * Lq + q)) * Dm + h * HD;
#pragma unroll
    for (int nt = 0; nt < 4; ++nt) {
      f32x4 o = oacc[qf][nt];
      uint2 pkd;
      pkd.x = pk2(o[0] * linv[qf], o[1] * linv[qf]);
      pkd.y = pk2(o[2] * linv[qf], o[3] * linv[qf]);
      *(uint2*)&Oa[rowb + nt * 16 + quad * 4] = pkd;
    }
  }
}

// ---------------- launcher ----------------
extern "C" void kernel_launch(void* const* d_in, const int* in_sizes, int n_in,
                              void* d_out, int out_size, void* d_ws, size_t ws_size,
                              hipStream_t stream) {
  const float* q  = (const float*)d_in[0];
  const float* k  = (const float*)d_in[1];
  const float* v  = (const float*)d_in[2];
  const float* Wq = (const float*)d_in[3];
  const float* bq = (const float*)d_in[4];
  const float* Wk = (const float*)d_in[5];
  const float* bk = (const float*)d_in[6];
  const float* Wv = (const float*)d_in[7];
  const float* bv = (const float*)d_in[8];
  const float* Wo = (const float*)d_in[9];
  const float* bo = (const float*)d_in[10];

  const int NA = Bsz * Lq * Dm;  // 8388608
  u16* abuf = (u16*)d_ws;            // [3][M][K] activations bf16; later Oa
  u16* Qh   = abuf + (size_t)3 * NA;
  u16* Kh   = Qh   + NA;
  u16* Vtg  = Kh   + NA;
  u16* wqb  = Vtg  + NA;
  u16* wkb  = wqb  + 1048576;
  u16* wvb  = wkb  + 1048576;
  u16* wob  = wvb  + 1048576;

  castw<<<dim3(512, 4), 256, 0, stream>>>(Wq, Wk, Wv, Wo, wqb, wkb, wvb, wob);
  castk3<<<dim3(NA / 2048, 3), 256, 0, stream>>>(q, k, v, abuf);

  qkv_gemm<<<dim3(8, 64, 3), 256, 0, stream>>>(abuf, wqb, wkb, wvb, bq, bk, bv, Qh, Kh, Vtg);

  attn4<<<dim3(Lq / 256, Bsz * NH), 256, 0, stream>>>(Qh, Kh, Vtg, abuf);

  gemm_wo<<<dim3(16, 64), 256, 0, stream>>>(abuf, wob, bo, (float*)d_out);
}

// Round 10
// 340.267 us; speedup vs baseline: 1.0930x; 1.0338x over previous
//
#include <hip/hip_runtime.h>

// MultiHead attention, B=4 L=2048 D=1024 H=16 HD=64.
// R18: attn4 KVBLK 64->128 (single lever). R17 counters: MfmaUtil 36.6 +
// VALUBusy 42 = 79% combined issue, conflicts 0, 2 waves/SIMD -> remaining
// ~21% is per-iteration barrier/drain stall. Halve barrier count 32->16 by
// staging 128 kpos per tile: Ks [2][128][64], Vt [2][64][128], 64KB LDS
// (still 2 blocks/CU). Inner compute = 4x unchanged 32-kpos windows; k
// accumulation order preserved -> absmax must stay bit-identical 1.464844e-3.
// K staging: R17 qkv geometry (key=lane>>3, i-invariant). V staging: rows are
// 256B=16 chunks; gl_lds instr i, lane l writes row 4i+(l>>4) phys chunk
// l&15, so key=(4i+(l>>4))&7=(l>>4)|((i&1)<<2) -> source logical chunk
// (l&15)^key, folded into 4 per-instr pointers. Reads keep chunk^(r16&7).
// qkv_gemm (R17: BK=64+swizzle), gemm_wo, casts, attn compute unchanged.

#define Bsz 4
#define Lq 2048
#define Dm 1024
#define NH 16
#define HD 64
// 0.125 * log2(e): folded into Wq/bq so attention uses exp2 directly
#define QSCALE 0.18033688011112042f

typedef unsigned short u16;
typedef __attribute__((ext_vector_type(4))) short bf16x4;
typedef __attribute__((ext_vector_type(8))) short short8;
typedef __attribute__((ext_vector_type(4))) float f32x4;

#define MFMA32(a, b, c) __builtin_amdgcn_mfma_f32_16x16x32_bf16(a, b, c, 0, 0, 0)

typedef __attribute__((address_space(3))) unsigned su32;
typedef __attribute__((address_space(1))) unsigned gu32;
__device__ __forceinline__ void gl_lds16(const u16* g, u16* l) {
  __builtin_amdgcn_global_load_lds((gu32*)(g), (su32*)(l), 16, 0, 0);
}

__device__ __forceinline__ u16 f2b(float x) {
  unsigned u = __builtin_bit_cast(unsigned, x);
  return (u16)((u + 0x7fffu + ((u >> 16) & 1u)) >> 16);  // RNE
}
__device__ __forceinline__ unsigned pk2(float a, float b) {
  return (unsigned)f2b(a) | ((unsigned)f2b(b) << 16);
}
// round-half-up bf16 pair pack via v_perm: lo=bf16(a), hi=bf16(b)
__device__ __forceinline__ unsigned pk2p(float a, float b) {
  return __builtin_amdgcn_perm(__builtin_bit_cast(unsigned, b) + 0x8000u,
                               __builtin_bit_cast(unsigned, a) + 0x8000u, 0x07060302u);
}
// packed bf16 pair, RTZ (single VALU op) — P-weights only, never outputs
__device__ __forceinline__ unsigned cvtpk(float a, float b) {
  unsigned r;
  asm("v_cvt_pk_bf16_f32 %0, %1, %2" : "=v"(r) : "v"(a), "v"(b));
  return r;
}
__device__ __forceinline__ float fexp2(float x) {
#if __has_builtin(__builtin_amdgcn_exp2f)
  return __builtin_amdgcn_exp2f(x);
#else
  return exp2f(x);
#endif
}

// ---------------- fused triple activation cast fp32 -> bf16 ----------------
__global__ void castk3(const float* __restrict__ q, const float* __restrict__ k,
                       const float* __restrict__ v, u16* __restrict__ dst) {
  const float* s = blockIdx.y == 0 ? q : (blockIdx.y == 1 ? k : v);
  u16* d = dst + (size_t)blockIdx.y * (Bsz * Lq * Dm);
  int i = (blockIdx.x * 256 + threadIdx.x) * 8;
  float4 a = *(const float4*)(s + i);
  float4 b = *(const float4*)(s + i + 4);
  short8 o;
  o[0] = (short)f2b(a.x); o[1] = (short)f2b(a.y);
  o[2] = (short)f2b(a.z); o[3] = (short)f2b(a.w);
  o[4] = (short)f2b(b.x); o[5] = (short)f2b(b.y);
  o[6] = (short)f2b(b.z); o[7] = (short)f2b(b.w);
  *(short8*)(d + i) = o;
}

// fused 4-weight cast, blockIdx.y selects matrix
__global__ void castw(const float* __restrict__ s0, const float* __restrict__ s1,
                      const float* __restrict__ s2, const float* __restrict__ s3,
                      u16* __restrict__ d0, u16* __restrict__ d1,
                      u16* __restrict__ d2, u16* __restrict__ d3) {
  const float* s; u16* d; float sc = 1.0f;
  switch (blockIdx.y) {
    case 0: s = s0; d = d0; sc = QSCALE; break;
    case 1: s = s1; d = d1; break;
    case 2: s = s2; d = d2; break;
    default: s = s3; d = d3; break;
  }
  int i = (blockIdx.x * 256 + threadIdx.x) * 8;
  float4 a = *(const float4*)(s + i);
  float4 b = *(const float4*)(s + i + 4);
  short8 o;
  o[0] = (short)f2b(a.x * sc); o[1] = (short)f2b(a.y * sc);
  o[2] = (short)f2b(a.z * sc); o[3] = (short)f2b(a.w * sc);
  o[4] = (short)f2b(b.x * sc); o[5] = (short)f2b(b.y * sc);
  o[6] = (short)f2b(b.z * sc); o[7] = (short)f2b(b.w * sc);
  *(short8*)(d + i) = o;
}

// ---------------- fused QKV projection GEMM ----------------
// grid (8, 64, 3). z: {q->Qh (scaled), k->Kh, v->Vtg (transposed+permuted)}.
// BK=64, XOR-swizzled LDS (attn4 geometry), 2 barriers per K-step, 16 steps.
__global__ __launch_bounds__(256) void qkv_gemm(
    const u16* __restrict__ Ab,
    const u16* __restrict__ Wqb, const u16* __restrict__ Wkb, const u16* __restrict__ Wvb,
    const float* __restrict__ bq, const float* __restrict__ bk, const float* __restrict__ bv,
    u16* __restrict__ Qh, u16* __restrict__ Kh, u16* __restrict__ Vtg)
{
  __shared__ __align__(16) u16 As[128 * 64];   // [row][64], chunk-swizzled
  __shared__ __align__(16) u16 Bs[128 * 64];
  const int z = blockIdx.z;
  const u16* A  = Ab + (size_t)z * (Bsz * Lq * Dm);
  const u16* Bt = z == 0 ? Wqb : (z == 1 ? Wkb : Wvb);
  const float* bias = z == 0 ? bq : (z == 1 ? bk : bv);
  const float bscale = z == 0 ? QSCALE : 1.0f;

  const int tid  = threadIdx.x;
  const int lane = tid & 63;
  const int wave = tid >> 6;
  const int quad = lane >> 4;
  const int r16  = lane & 15;
  const int wm   = (wave >> 1) * 64;
  const int wn   = (wave & 1) * 64;
  const int m0   = blockIdx.y * 128;
  const int n0   = blockIdx.x * 128;

  // Staging: wave stages rows [wave*32, wave*32+32) in 4 gl_lds of 8 rows.
  // Instr i, lane l -> LDS elem wave*2048 + i*512 + l*8; phys chunk l&7,
  // row&7 = l>>3 -> source logical chunk = (l&7)^(l>>3).
  const int srcc = ((lane & 7) ^ (lane >> 3)) * 8;   // source chunk offset, elems
  const int r0   = wave * 32 + (lane >> 3);          // tile row for instr 0
  const u16* ga = A  + (size_t)(m0 + r0) * Dm + srcc;
  const u16* gb = Bt + (size_t)(n0 + r0) * Dm + srcc;
  u16* la = As + wave * 2048;
  u16* lb = Bs + wave * 2048;

  f32x4 acc[4][4] = {};
  const int sx = r16 & 7;   // read-side swizzle key (read rows are 16k+r16)

  for (int k0 = 0; k0 < Dm; k0 += 64) {
#pragma unroll
    for (int i = 0; i < 4; ++i) {
      gl_lds16(ga + k0 + (size_t)(8 * i) * Dm, la + i * 512);
      gl_lds16(gb + k0 + (size_t)(8 * i) * Dm, lb + i * 512);
    }
    __syncthreads();

    short8 af[4][2], bfr[4][2];
#pragma unroll
    for (int mt = 0; mt < 4; ++mt)
#pragma unroll
      for (int kk = 0; kk < 2; ++kk)
        af[mt][kk] = *(const short8*)&As[(wm + mt * 16 + r16) * 64 + ((kk * 4 + quad) ^ sx) * 8];
#pragma unroll
    for (int nt = 0; nt < 4; ++nt)
#pragma unroll
      for (int kk = 0; kk < 2; ++kk)
        bfr[nt][kk] = *(const short8*)&Bs[(wn + nt * 16 + r16) * 64 + ((kk * 4 + quad) ^ sx) * 8];
    // kk outer so each acc sees k in increasing order (bit-identical to BK=32)
#pragma unroll
    for (int kk = 0; kk < 2; ++kk)
#pragma unroll
      for (int mt = 0; mt < 4; ++mt)
#pragma unroll
        for (int nt = 0; nt < 4; ++nt)
          acc[mt][nt] = MFMA32(af[mt][kk], bfr[nt][kk], acc[mt][nt]);
    __syncthreads();
  }

#pragma unroll
  for (int mt = 0; mt < 4; ++mt) {
#pragma unroll
    for (int nt = 0; nt < 4; ++nt) {
      int n = n0 + wn + nt * 16 + r16;
      float bv_ = bias[n] * bscale;
      if (z == 2) {
        // V: transposed head-split Vtg[bh][d][l'], column-permuted within each
        // 32-block: l' = (l&~31) | q<<3 | w<<2 | j  (q=(l>>2)&3, w=(l>>4)&1)
        // so attention's b128 A-frag slot (quad,i=4w+j) carries the kpos that
        // the P B-frag holds in the same slot.
        int m_base = m0 + wm + mt * 16 + quad * 4;
        int b = m_base >> 11, l0 = m_base & 2047;
        int lp = (l0 & ~31) | (((l0 >> 2) & 3) << 3) | (((l0 >> 4) & 1) << 2);
        int h = n >> 6, d = n & 63;
        u16* dst = Vtg + (((size_t)(b * NH + h)) * HD + d) * Lq + lp;
        uint2 pkd;
        pkd.x = pk2(acc[mt][nt][0] + bv_, acc[mt][nt][1] + bv_);
        pkd.y = pk2(acc[mt][nt][2] + bv_, acc[mt][nt][3] + bv_);
        *(uint2*)dst = pkd;
      } else {
        u16* dst = z == 0 ? Qh : Kh;
#pragma unroll
        for (int j = 0; j < 4; ++j) {
          int m = m0 + wm + mt * 16 + quad * 4 + j;
          int b = m >> 11, l = m & 2047;
          int h = n >> 6,  d = n & 63;
          dst[(((size_t)(b * NH + h)) * Lq + l) * HD + d] = f2b(acc[mt][nt][j] + bv_);
        }
      }
    }
  }
}

// ---------------- Wo GEMM: 128x64 tile, fp32 out ----------------
__global__ __launch_bounds__(256) void gemm_wo(
    const u16* __restrict__ A, const u16* __restrict__ Bt,
    const float* __restrict__ bias, float* __restrict__ C)
{
  __shared__ __align__(16) u16 As[128 * 32];
  __shared__ __align__(16) u16 Bs[64 * 32];
  const int tid  = threadIdx.x;
  const int lane = tid & 63;
  const int wave = tid >> 6;
  const int quad = lane >> 4;
  const int r16  = lane & 15;
  const int wm   = wave * 32;
  const int m0   = blockIdx.y * 128;
  const int n0   = blockIdx.x * 64;

  const u16* ga = A  + (size_t)(m0 + wave * 32 + (lane >> 2)) * Dm + (lane & 3) * 8;
  const u16* gb = Bt + (size_t)(n0 + wave * 16 + (lane >> 2)) * Dm + (lane & 3) * 8;
  u16* la = As + wave * 1024;
  u16* lb = Bs + wave * 512;

  f32x4 acc[2][4] = {};

  for (int k0 = 0; k0 < Dm; k0 += 32) {
    gl_lds16(ga + k0, la);
    gl_lds16(ga + k0 + 16 * Dm, la + 512);
    gl_lds16(gb + k0, lb);
    __syncthreads();

    short8 af[2], bfr[4];
#pragma unroll
    for (int mt = 0; mt < 2; ++mt) af[mt]  = *(const short8*)&As[(wm + mt * 16 + r16) * 32 + quad * 8];
#pragma unroll
    for (int nt = 0; nt < 4; ++nt) bfr[nt] = *(const short8*)&Bs[(nt * 16 + r16) * 32 + quad * 8];
#pragma unroll
    for (int mt = 0; mt < 2; ++mt)
#pragma unroll
      for (int nt = 0; nt < 4; ++nt)
        acc[mt][nt] = MFMA32(af[mt], bfr[nt], acc[mt][nt]);
    __syncthreads();
  }

#pragma unroll
  for (int mt = 0; mt < 2; ++mt) {
#pragma unroll
    for (int nt = 0; nt < 4; ++nt) {
      int n = n0 + nt * 16 + r16;
      float bv = bias[n];
#pragma unroll
      for (int j = 0; j < 4; ++j) {
        int m = m0 + wm + mt * 16 + quad * 4 + j;
        C[(size_t)m * Dm + n] = acc[mt][nt][j] + bv;
      }
    }
  }
}

// ---------------- fused flash attention (S^T form, K=32 PV) ----------------
// Qh (pre-scaled), Kh: [bh][L][HD] bf16. Vtg: [bh][HD][L] bf16, col-permuted.
// Oa: [B*L][D] bf16 row-major. Block: 4 waves x 64 q = 256 q; k-tiles of 128.
// LDS 2-deep double buffer (64KB), XOR-swizzled, filled by global_load_lds
// with pre-swizzled global sources.
__global__ __launch_bounds__(256) void attn4(
    const u16* __restrict__ Qh, const u16* __restrict__ Kh,
    const u16* __restrict__ Vtg, u16* __restrict__ Oa)
{
  const int bh = blockIdx.y;   // 0..63
  const int qt = blockIdx.x;   // 0..7
  const int tid = threadIdx.x, lane = tid & 63, wave = tid >> 6;
  const int quad = lane >> 4, r16 = lane & 15;

  __shared__ __align__(16) u16 Ks[2][128][64];   // [buf][kpos][d], chunk-swizzled
  __shared__ __align__(16) u16 Vt[2][64][128];   // [buf][d][kpos'] (permuted), chunk-swizzled

  const int qbase = qt * 256 + wave * 64;
  short8 aq[4][2];
#pragma unroll
  for (int qf = 0; qf < 4; ++qf) {
    const size_t qrow = ((size_t)bh * Lq + qbase + qf * 16 + r16) * HD;
    aq[qf][0] = *(const short8*)(Qh + qrow + quad * 8);
    aq[qf][1] = *(const short8*)(Qh + qrow + 32 + quad * 8);
  }

  const short8 ones8 = {0x3F80, 0x3F80, 0x3F80, 0x3F80, 0x3F80, 0x3F80, 0x3F80, 0x3F80};

  f32x4 oacc[4][4] = {};
  f32x4 lacc[4] = {};   // ones*P: every row = column sum of P; col = r16 = own q

  // --- K staging (rows 128, 64 elems = 8 chunks/row) ---
  // Wave stages rows [wave*32, +32) in 4 instrs of 8 rows: instr i, lane l ->
  // LDS elem wave*2048 + i*512 + l*8; row = wave*32 + 8i + (l>>3), phys chunk
  // l&7, key = row&7 = l>>3 (i-invariant) -> source chunk (l&7)^(l>>3).
  const int ksrc = ((lane & 7) ^ (lane >> 3)) * 8;
  const u16* kg0 = Kh + ((size_t)bh * Lq + wave * 32 + (lane >> 3)) * HD + ksrc;
  // --- V staging (rows 64, 128 elems = 16 chunks/row) ---
  // Wave stages rows [wave*16, +16) in 4 instrs of 4 rows: instr i, lane l ->
  // LDS elem wave*2048 + i*512 + l*8; row = wave*16 + 4i + (l>>4), phys chunk
  // l&15, key = row&7 = (4i+(l>>4))&7 = (l>>4)|((i&1)<<2) -> source chunk
  // (l&15)^key, i-dependent: fold into 4 per-instr pointers.
  const u16* vgp[4];
#pragma unroll
  for (int i = 0; i < 4; ++i) {
    int vrow = wave * 16 + 4 * i + (lane >> 4);
    int vkey = (lane >> 4) | ((i & 1) << 2);
    int vsc  = ((lane & 15) ^ vkey) * 8;
    vgp[i] = Vtg + ((size_t)bh * HD + vrow) * Lq + vsc;
  }
  u16* ksb = &Ks[0][0][0];
  u16* vtb = &Vt[0][0][0];
  const int ldst = wave * 2048;   // wave-uniform LDS base within a buffer, elems

  // prologue: stage tile 0 into buffer 0
#pragma unroll
  for (int i = 0; i < 4; ++i) {
    gl_lds16(kg0 + (size_t)(8 * i) * HD, ksb + ldst + i * 512);
    gl_lds16(vgp[i],                     vtb + ldst + i * 512);
  }

  const int sx = r16 & 7;           // read-side swizzle key (rows are 16k+r16)

  for (int t = 0; t < 16; ++t) {
    // barrier: compiler emits s_waitcnt vmcnt(0) before s_barrier, draining
    // this wave's tile-t loads; barrier gives cross-wave visibility.
    __syncthreads();
    const int cur = (t & 1) * 8192;
    const int nxt = 8192 - cur;
    if (t < 15) {
      const size_t ko = (size_t)(t + 1) * (128 * HD);
      const int    vo = (t + 1) * 128;
#pragma unroll
      for (int i = 0; i < 4; ++i) {
        gl_lds16(kg0 + ko + (size_t)(8 * i) * HD, ksb + nxt + ldst + i * 512);
        gl_lds16(vgp[i] + vo,                     vtb + nxt + ldst + i * 512);
      }
    }

#pragma unroll
    for (int w = 0; w < 4; ++w) {
      // K fragments for the two 16-kpos chunks of this 32-window (shared
      // across all 4 q fragments)
      short8 kf[2][2];
#pragma unroll
      for (int mtl = 0; mtl < 2; ++mtl) {
        const int mt = 2 * w + mtl;
        kf[mtl][0] = *(const short8*)(ksb + cur + (mt * 16 + r16) * 64 + ((quad    ) ^ sx) * 8);
        kf[mtl][1] = *(const short8*)(ksb + cur + (mt * 16 + r16) * 64 + ((quad + 4) ^ sx) * 8);
      }
      // V A-frags for this window (permuted layout -> direct b128), shared
      // across all 4 q fragments
      short8 vf[4];
#pragma unroll
      for (int nt = 0; nt < 4; ++nt)
        vf[nt] = *(const short8*)(vtb + cur + (nt * 16 + r16) * 128 + ((w * 4 + quad) ^ sx) * 8);
      // per-qf: S^T, softmax, PV at K=32 (4 independent chains for ILP).
      // P packed RTZ; lsum MFMA-summed from the SAME truncated P, so the
      // RTZ bias cancels exactly in the final O = num/den ratio.
#pragma unroll
      for (int qf = 0; qf < 4; ++qf) {
        f32x4 sa = {}, sb = {};
        sa = MFMA32(kf[0][0], aq[qf][0], sa);
        sa = MFMA32(kf[0][1], aq[qf][1], sa);
        sb = MFMA32(kf[1][0], aq[qf][0], sb);
        sb = MFMA32(kf[1][1], aq[qf][1], sb);
        uint4 pu;
        pu.x = cvtpk(fexp2(sa[0]), fexp2(sa[1]));
        pu.y = cvtpk(fexp2(sa[2]), fexp2(sa[3]));
        pu.z = cvtpk(fexp2(sb[0]), fexp2(sb[1]));
        pu.w = cvtpk(fexp2(sb[2]), fexp2(sb[3]));
        short8 pb = __builtin_bit_cast(short8, pu);
        lacc[qf] = MFMA32(ones8, pb, lacc[qf]);
#pragma unroll
        for (int nt = 0; nt < 4; ++nt)
          oacc[qf][nt] = MFMA32(vf[nt], pb, oacc[qf][nt]);
      }
    }
  }

  const int b = bh >> 4, h = bh & 15;
  // lacc: ones*P rows all equal the P column-sum; col = r16 = this lane's q
  // in the epilogue mapping below -> no cross-lane reduction needed.
  float linv[4];
#pragma unroll
  for (int qf = 0; qf < 4; ++qf) linv[qf] = 1.0f / lacc[qf][0];
#pragma unroll
  for (int qf = 0; qf < 4; ++qf) {
    int q = qbase + qf * 16 + r16;
    size_t rowb = ((size_t)(b * Lq + q)) * Dm + h * HD;
#pragma unroll
    for (int nt = 0; nt < 4; ++nt) {
      f32x4 o = oacc[qf][nt];
      uint2 pkd;
      pkd.x = pk2(o[0] * linv[qf], o[1] * linv[qf]);
      pkd.y = pk2(o[2] * linv[qf], o[3] * linv[qf]);
      *(uint2*)&Oa[rowb + nt * 16 + quad * 4] = pkd;
    }
  }
}

// ---------------- launcher ----------------
extern "C" void kernel_launch(void* const* d_in, const int* in_sizes, int n_in,
                              void* d_out, int out_size, void* d_ws, size_t ws_size,
                              hipStream_t stream) {
  const float* q  = (const float*)d_in[0];
  const float* k  = (const float*)d_in[1];
  const float* v  = (const float*)d_in[2];
  const float* Wq = (const float*)d_in[3];
  const float* bq = (const float*)d_in[4];
  const float* Wk = (const float*)d_in[5];
  const float* bk = (const float*)d_in[6];
  const float* Wv = (const float*)d_in[7];
  const float* bv = (const float*)d_in[8];
  const float* Wo = (const float*)d_in[9];
  const float* bo = (const float*)d_in[10];

  const int NA = Bsz * Lq * Dm;  // 8388608
  u16* abuf = (u16*)d_ws;            // [3][M][K] activations bf16; later Oa
  u16* Qh   = abuf + (size_t)3 * NA;
  u16* Kh   = Qh   + NA;
  u16* Vtg  = Kh   + NA;
  u16* wqb  = Vtg  + NA;
  u16* wkb  = wqb  + 1048576;
  u16* wvb  = wkb  + 1048576;
  u16* wob  = wvb  + 1048576;

  castw<<<dim3(512, 4), 256, 0, stream>>>(Wq, Wk, Wv, Wo, wqb, wkb, wvb, wob);
  castk3<<<dim3(NA / 2048, 3), 256, 0, stream>>>(q, k, v, abuf);

  qkv_gemm<<<dim3(8, 64, 3), 256, 0, stream>>>(abuf, wqb, wkb, wvb, bq, bk, bv, Qh, Kh, Vtg);

  attn4<<<dim3(Lq / 256, Bsz * NH), 256, 0, stream>>>(Qh, Kh, Vtg, abuf);

  gemm_wo<<<dim3(16, 64), 256, 0, stream>>>(abuf, wob, bo, (float*)d_out);
}